// Round 1
// baseline (651.982 us; speedup 1.0000x reference)
//
#include <hip/hip_runtime.h>
#include <hip/hip_bf16.h>
#include <math.h>

// Problem constants
#define CDIM 256
#define TDIM 512
#define T2   1024
#define NB   64      // N*H batches
#define MTOT 524288.0f   // T*2T elements per batch for LN

typedef __bf16 bf16x8 __attribute__((ext_vector_type(8)));
typedef float  f32x4  __attribute__((ext_vector_type(4)));

__device__ __forceinline__ ushort f2bf(float f) {
  union { float f; unsigned u; } v; v.f = f;
  unsigned r = v.u + 0x7fffu + ((v.u >> 16) & 1u);
  return (ushort)(r >> 16);
}
__device__ __forceinline__ float bf2f(ushort h) {
  union { unsigned u; float f; } v; v.u = ((unsigned)h) << 16;
  return v.f;
}
__device__ __forceinline__ float gelu_exact(float x) {
  return 0.5f * x * (1.0f + erff(x * 0.7071067811865475f));
}

// int-cast route avoids clang addrspace-cast diagnostics; low 32 bits of a
// generic LDS pointer are the LDS byte offset on gfx9+.
#define TO_LDS(p)  ((__attribute__((address_space(3))) void*)(unsigned)(uintptr_t)(p))
#define TO_GLB(p)  ((const __attribute__((address_space(1))) void*)(uintptr_t)(p))
#define GLOAD_LDS16(g, l) __builtin_amdgcn_global_load_lds(TO_GLB(g), TO_LDS(l), 16, 0, 0)

// ---------------------------------------------------------------- projections
// qp/kp/vp[n, o, t] = sum_c W[o,c] * x[n,c,t]
__global__ __launch_bounds__(256)
void proj_kernel(const float* __restrict__ x, const float* __restrict__ Wq,
                 const float* __restrict__ Wk, const float* __restrict__ Wv,
                 float* __restrict__ qp, float* __restrict__ kp, float* __restrict__ vp) {
  int t = blockIdx.x * 256 + threadIdx.x;   // 2 x-tiles
  int o = blockIdx.y;                        // 256
  int n = blockIdx.z;                        // 8
  const float* xn = x + (long)n * CDIM * TDIM;
  float aq = 0.f, ak = 0.f, av = 0.f;
  for (int c = 0; c < CDIM; ++c) {
    float xv = xn[c * TDIM + t];
    aq = fmaf(Wq[o * CDIM + c], xv, aq);
    ak = fmaf(Wk[o * CDIM + c], xv, ak);
    av = fmaf(Wv[o * CDIM + c], xv, av);
  }
  long idx = ((long)n * 256 + o) * TDIM + t;
  qp[idx] = aq; kp[idx] = ak; vp[idx] = av;
}

// ------------------------------------------------- circulant weights, transposed
// CPT[o][kk], kk = 2s+r :  cp[kk][o] = w[r, (o - s*stride) mod outdim]
__global__ __launch_bounds__(256)
void build_cpt_kernel(const float* __restrict__ w, ushort* __restrict__ cpt,
                      int outdim, int stride) {
  int i = blockIdx.x * 256 + threadIdx.x;   // outdim*1024 elements
  int o  = i >> 10;
  int kk = i & 1023;
  int s = kk >> 1, r = kk & 1;
  float v = w[r * outdim + ((o - s * stride) & (outdim - 1))];
  cpt[i] = f2bf(v);
}

// ------------------------------------------------------------------- P0 build
// P0[b, t, 2s] = (q.k)/sqrt(32) ; P0[b, t, 2s+1] = |s-t|/511
__global__ __launch_bounds__(256)
void build_p0_kernel(const float* __restrict__ qp, const float* __restrict__ kp,
                     ushort* __restrict__ P) {
  int s = blockIdx.x * 256 + threadIdx.x;   // 2 tiles
  int t = blockIdx.y;                        // 512
  int b = blockIdx.z;                        // 64 = n*8+h
  int n = b >> 3, h = b & 7;
  const float* qrow = qp + ((long)n * 256 + h * 32) * TDIM + t;  // stride TDIM per d
  const float* krow = kp + ((long)n * 256 + h * 32) * TDIM + s;
  float acc = 0.f;
#pragma unroll
  for (int d = 0; d < 32; ++d) acc = fmaf(qrow[d * TDIM], krow[d * TDIM], acc);
  acc *= 0.17677669529663687f;   // 1/sqrt(32)
  float pd = fabsf((float)(s - t)) * (1.0f / 511.0f);
  ushort2 pr; pr.x = f2bf(acc); pr.y = f2bf(pd);
  *(ushort2*)(P + (((long)b * TDIM + t) * T2 + 2 * s)) = pr;
}

// ------------------------------------------------------------------ bf16 GEMM
// Y[b] = A[b] (Mx1024, row-major) * BT[b] (ncols x 1024, row-major)^T
// m97 structure: 128x128 tile, BK=32, 4 waves (2x2, 64x64 each), global_load_lds.
// !FINAL: bf16 out + LN stats atomics.  FINAL: f32 out (already "transposed" L).
template<bool FINAL>
__global__ __launch_bounds__(256)
void gemm_bt_kernel(const ushort* __restrict__ A, long aStride,
                    const ushort* __restrict__ BT, long bStride,
                    void* __restrict__ Out, int ncols, float* __restrict__ stats) {
  __shared__ ushort Asm[128 * 32];
  __shared__ ushort Bsm[128 * 32];
  const int tid = threadIdx.x;
  const int bm = blockIdx.x, bn = blockIdx.y, b = blockIdx.z;
  const ushort* Ab = A  + (long)b * aStride + (long)bm * 128 * 1024;
  const ushort* Bb = BT + (long)b * bStride + (long)bn * 128 * 1024;
  const int lrow = tid >> 2;            // 0..63
  const int lk   = (tid & 3) * 8;
  const ushort* ga = Ab + (long)lrow * 1024 + lk;
  const ushort* gb = Bb + (long)lrow * 1024 + lk;
  char* asmb = (char*)Asm + tid * 16;   // linear LDS dest: wave-uniform + lane*16
  char* bsmb = (char*)Bsm + tid * 16;
  const int lane = tid & 63;
  const int wm = (tid >> 7) & 1;        // wave row (2x2 wave grid)
  const int wn = (tid >> 6) & 1;        // wave col
  const int fr = lane & 15;
  const int fq = lane >> 4;
  f32x4 acc[4][4] = {};

  for (int kt = 0; kt < 1024; kt += 32) {
    GLOAD_LDS16(ga + kt,             asmb);
    GLOAD_LDS16(ga + kt + 64 * 1024, asmb + 4096);
    GLOAD_LDS16(gb + kt,             bsmb);
    GLOAD_LDS16(gb + kt + 64 * 1024, bsmb + 4096);
    __syncthreads();
    bf16x8 af[4], bfv[4];
#pragma unroll
    for (int mi = 0; mi < 4; ++mi)
      af[mi] = *(const bf16x8*)(Asm + (wm * 64 + mi * 16 + fr) * 32 + fq * 8);
#pragma unroll
    for (int ni = 0; ni < 4; ++ni)
      bfv[ni] = *(const bf16x8*)(Bsm + (wn * 64 + ni * 16 + fr) * 32 + fq * 8);
#pragma unroll
    for (int mi = 0; mi < 4; ++mi)
#pragma unroll
      for (int ni = 0; ni < 4; ++ni)
        acc[mi][ni] = __builtin_amdgcn_mfma_f32_16x16x32_bf16(af[mi], bfv[ni], acc[mi][ni], 0, 0, 0);
    __syncthreads();
  }

  const int r0 = bm * 128 + wm * 64;
  const int c0 = bn * 128 + wn * 64;
  if (!FINAL) {
    ushort* Yb = (ushort*)Out + (long)b * 512 * ncols;
    float s1 = 0.f, s2 = 0.f;
#pragma unroll
    for (int mi = 0; mi < 4; ++mi)
#pragma unroll
      for (int ni = 0; ni < 4; ++ni)
#pragma unroll
        for (int r = 0; r < 4; ++r) {
          float v = acc[mi][ni][r];
          s1 += v; s2 += v * v;
          int row = r0 + mi * 16 + fq * 4 + r;   // C/D: row=(lane>>4)*4+reg
          int col = c0 + ni * 16 + fr;            //      col=lane&15
          Yb[(long)row * ncols + col] = f2bf(v);
        }
    float* redA = (float*)Asm;
    float* redB = (float*)Bsm;
    redA[tid] = s1; redB[tid] = s2;
    __syncthreads();
    for (int off = 128; off > 0; off >>= 1) {
      if (tid < off) { redA[tid] += redA[tid + off]; redB[tid] += redB[tid + off]; }
      __syncthreads();
    }
    if (tid == 0) {
      atomicAdd(&stats[b * 2],     redA[0]);
      atomicAdd(&stats[b * 2 + 1], redB[0]);
    }
  } else {
    float* Lb = (float*)Out + (long)b * 512 * 512;
#pragma unroll
    for (int mi = 0; mi < 4; ++mi)
#pragma unroll
      for (int ni = 0; ni < 4; ++ni)
#pragma unroll
        for (int r = 0; r < 4; ++r) {
          int row = r0 + mi * 16 + fq * 4 + r;
          int col = c0 + ni * 16 + fr;
          Lb[(long)row * 512 + col] = acc[mi][ni][r];
        }
  }
}

// --------------------------------------------- LN + gelu + pair-transpose fused
// P'[b, s, 2t+r] = gelu( (Y[b,t,2s+r]-mu)*rstd*g[t,2s+r] + bias[t,2s+r] )
__global__ __launch_bounds__(256)
void apply_kernel(const ushort* __restrict__ Y, const float* __restrict__ stats,
                  const float* __restrict__ g, const float* __restrict__ bia,
                  ushort* __restrict__ P) {
  __shared__ ushort2 tile[32][33];
  int ti = blockIdx.x;   // 16 t-tiles
  int si = blockIdx.y;   // 16 s-tiles
  int b  = blockIdx.z;   // 64
  float mu  = stats[b * 2] * (1.0f / MTOT);
  float var = stats[b * 2 + 1] * (1.0f / MTOT) - mu * mu;
  float rstd = rsqrtf(var + 1e-5f);
  int tx = threadIdx.x & 31, ty = threadIdx.x >> 5;
  const ushort* Yb = Y + (long)b * 512 * 1024;
#pragma unroll
  for (int i = 0; i < 4; ++i) {
    int t  = ti * 32 + ty + i * 8;
    int sp = si * 32 + tx;
    ushort2 yv = *(const ushort2*)(Yb + (long)t * 1024 + 2 * sp);
    float2 gv = *(const float2*)(g   + (long)t * 1024 + 2 * sp);
    float2 bv = *(const float2*)(bia + (long)t * 1024 + 2 * sp);
    float y0 = (bf2f(yv.x) - mu) * rstd * gv.x + bv.x;
    float y1 = (bf2f(yv.y) - mu) * rstd * gv.y + bv.y;
    ushort2 o; o.x = f2bf(gelu_exact(y0)); o.y = f2bf(gelu_exact(y1));
    tile[ty + i * 8][tx] = o;
  }
  __syncthreads();
  ushort* Pb = P + (long)b * 512 * 1024;
#pragma unroll
  for (int i = 0; i < 4; ++i) {
    int srow = si * 32 + ty + i * 8;
    int tcol = ti * 32 + tx;
    ushort2 v = tile[tx][ty + i * 8];
    *(ushort2*)(Pb + (long)srow * 1024 + 2 * tcol) = v;
  }
}

// ------------------------------------------------------------------- softmax
__global__ __launch_bounds__(256)
void softmax_kernel(float* __restrict__ L) {
  int wid = threadIdx.x >> 6, lane = threadIdx.x & 63;
  long row = (long)blockIdx.x * 4 + wid;   // 32768 rows total
  float* Lr = L + row * 512;
  float4 a = *(float4*)(Lr + lane * 8);
  float4 c = *(float4*)(Lr + lane * 8 + 4);
  float m = fmaxf(fmaxf(fmaxf(a.x, a.y), fmaxf(a.z, a.w)),
                  fmaxf(fmaxf(c.x, c.y), fmaxf(c.z, c.w)));
  for (int off = 32; off > 0; off >>= 1) m = fmaxf(m, __shfl_xor(m, off, 64));
  a.x = expf(a.x - m); a.y = expf(a.y - m); a.z = expf(a.z - m); a.w = expf(a.w - m);
  c.x = expf(c.x - m); c.y = expf(c.y - m); c.z = expf(c.z - m); c.w = expf(c.w - m);
  float s = a.x + a.y + a.z + a.w + c.x + c.y + c.z + c.w;
  for (int off = 32; off > 0; off >>= 1) s += __shfl_xor(s, off, 64);
  float inv = 1.0f / s;
  a.x *= inv; a.y *= inv; a.z *= inv; a.w *= inv;
  c.x *= inv; c.y *= inv; c.z *= inv; c.w *= inv;
  *(float4*)(Lr + lane * 8) = a;
  *(float4*)(Lr + lane * 8 + 4) = c;
}

// ------------------------------------------------------------------ attn @ V
// out[n, h*32+d, a] = sum_b attn[b(nh), a, bcol] * vp[n, h*32+d, bcol]
__global__ __launch_bounds__(256)
void av_kernel(const float* __restrict__ L, const float* __restrict__ vp,
               float* __restrict__ out) {
  __shared__ float vt[32 * 512];   // 64 KB
  int bh = blockIdx.x;  // 64
  int at = blockIdx.y;  // 16 tiles of 32 rows
  int n = bh >> 3, h = bh & 7;
  const float* vsrc = vp + ((long)n * 256 + h * 32) * 512;
  for (int i = threadIdx.x; i < 32 * 512 / 4; i += 256)
    ((float4*)vt)[i] = ((const float4*)vsrc)[i];
  __syncthreads();
  int a  = at * 32 + (threadIdx.x & 31);
  int d0 = (threadIdx.x >> 5) * 4;
  const float* Lr = L + ((long)bh * 512 + a) * 512;
  float acc0 = 0.f, acc1 = 0.f, acc2 = 0.f, acc3 = 0.f;
  for (int bcol = 0; bcol < 512; ++bcol) {
    float p = Lr[bcol];
    acc0 = fmaf(p, vt[(d0 + 0) * 512 + bcol], acc0);
    acc1 = fmaf(p, vt[(d0 + 1) * 512 + bcol], acc1);
    acc2 = fmaf(p, vt[(d0 + 2) * 512 + bcol], acc2);
    acc3 = fmaf(p, vt[(d0 + 3) * 512 + bcol], acc3);
  }
  float* ob = out + ((long)n * 256 + h * 32) * 512;
  ob[(d0 + 0) * 512 + a] = acc0;
  ob[(d0 + 1) * 512 + a] = acc1;
  ob[(d0 + 2) * 512 + a] = acc2;
  ob[(d0 + 3) * 512 + a] = acc3;
}

// -------------------------------------------------------------------- launch
extern "C" void kernel_launch(void* const* d_in, const int* in_sizes, int n_in,
                              void* d_out, int out_size, void* d_ws, size_t ws_size,
                              hipStream_t stream) {
  const float* x     = (const float*)d_in[0];
  const float* Wq    = (const float*)d_in[1];
  const float* Wk    = (const float*)d_in[2];
  const float* Wv    = (const float*)d_in[3];
  const float* m1w0  = (const float*)d_in[4];
  const float* m2w0  = (const float*)d_in[5];
  const float* m1w1  = (const float*)d_in[6];
  const float* m2w1  = (const float*)d_in[7];
  const float* ln1g0 = (const float*)d_in[8];
  const float* ln1b0 = (const float*)d_in[9];
  const float* ln2g0 = (const float*)d_in[10];
  const float* ln2b0 = (const float*)d_in[11];
  const float* ln1g1 = (const float*)d_in[12];
  const float* ln1b1 = (const float*)d_in[13];

  char* w = (char*)d_ws;
  float*  qp    = (float*) (w + 0);                 // 4 MB
  float*  kp    = (float*) (w + (4ull  << 20));     // 4 MB
  float*  vp    = (float*) (w + (8ull  << 20));     // 4 MB
  float*  stats = (float*) (w + (12ull << 20));     // 3*64*2 f32
  ushort* cpt0  = (ushort*)(w + (13ull << 20));     // 2 MB
  ushort* cpt1  = (ushort*)(w + (15ull << 20));     // 2 MB
  ushort* cpt2  = (ushort*)(w + (17ull << 20));     // 2 MB
  ushort* cpt3  = (ushort*)(w + (19ull << 20));     // 1 MB
  ushort* bufA  = (ushort*)(w + (20ull << 20));     // 64 MB
  ushort* bufB  = (ushort*)(w + (84ull << 20));     // 64 MB (also L as f32)
  float*  L     = (float*)bufB;
  float*  outp  = (float*)d_out;

  hipMemsetAsync(stats, 0, 3 * NB * 2 * sizeof(float), stream);

  proj_kernel<<<dim3(2, 256, 8), 256, 0, stream>>>(x, Wq, Wk, Wv, qp, kp, vp);
  build_cpt_kernel<<<4096, 256, 0, stream>>>(m1w0, cpt0, 1024, 2);
  build_cpt_kernel<<<4096, 256, 0, stream>>>(m2w0, cpt1, 1024, 2);
  build_cpt_kernel<<<4096, 256, 0, stream>>>(m1w1, cpt2, 1024, 2);
  build_cpt_kernel<<<2048, 256, 0, stream>>>(m2w1, cpt3, 512, 1);
  build_p0_kernel<<<dim3(2, 512, 64), 256, 0, stream>>>(qp, kp, bufA);

  gemm_bt_kernel<false><<<dim3(4, 8, 64), 256, 0, stream>>>(bufA, 512L * 1024, cpt0, 0, bufB, 1024, stats);
  apply_kernel<<<dim3(16, 16, 64), 256, 0, stream>>>(bufB, stats, ln1g0, ln1b0, bufA);
  gemm_bt_kernel<false><<<dim3(4, 8, 64), 256, 0, stream>>>(bufA, 512L * 1024, cpt1, 0, bufB, 1024, stats + 128);
  apply_kernel<<<dim3(16, 16, 64), 256, 0, stream>>>(bufB, stats + 128, ln2g0, ln2b0, bufA);
  gemm_bt_kernel<false><<<dim3(4, 8, 64), 256, 0, stream>>>(bufA, 512L * 1024, cpt2, 0, bufB, 1024, stats + 256);
  apply_kernel<<<dim3(16, 16, 64), 256, 0, stream>>>(bufB, stats + 256, ln1g1, ln1b1, bufA);
  // Final: L[b, a, t] = sum_k CPT3[a,k] * P3'[t,k]  (softmax-ready layout)
  gemm_bt_kernel<true><<<dim3(4, 4, 64), 256, 0, stream>>>(cpt3, 0, bufA, 512L * 1024, L, 512, nullptr);
  softmax_kernel<<<8192, 256, 0, stream>>>(L);
  av_kernel<<<dim3(64, 16), 256, 0, stream>>>(L, vp, outp);
}

// Round 2
// 561.920 us; speedup vs baseline: 1.1603x; 1.1603x over previous
//
#include <hip/hip_runtime.h>
#include <hip/hip_bf16.h>
#include <math.h>

// Problem constants
#define CDIM 256
#define TDIM 512
#define T2   1024
#define NB   64      // N*H batches
#define MTOT 524288.0f   // T*2T elements per batch for LN

typedef __bf16 bf16x8 __attribute__((ext_vector_type(8)));
typedef float  f32x4  __attribute__((ext_vector_type(4)));

__device__ __forceinline__ ushort f2bf(float f) {
  union { float f; unsigned u; } v; v.f = f;
  unsigned r = v.u + 0x7fffu + ((v.u >> 16) & 1u);
  return (ushort)(r >> 16);
}
__device__ __forceinline__ float bf2f(ushort h) {
  union { unsigned u; float f; } v; v.u = ((unsigned)h) << 16;
  return v.f;
}
__device__ __forceinline__ float gelu_exact(float x) {
  return 0.5f * x * (1.0f + erff(x * 0.7071067811865475f));
}

#define TO_LDS(p)  ((__attribute__((address_space(3))) void*)(unsigned)(uintptr_t)(p))
#define TO_GLB(p)  ((const __attribute__((address_space(1))) void*)(uintptr_t)(p))
#define GLOAD_LDS16(g, l) __builtin_amdgcn_global_load_lds(TO_GLB(g), TO_LDS(l), 16, 0, 0)

#define BAR()    asm volatile("s_barrier" ::: "memory")
#define WAITL()  asm volatile("s_waitcnt lgkmcnt(0)" ::: "memory")
#define WAITV4() asm volatile("s_waitcnt vmcnt(4)" ::: "memory")
#define WAITV0() asm volatile("s_waitcnt vmcnt(0)" ::: "memory")

// ---------------------------------------------------------------- projections
__global__ __launch_bounds__(256)
void proj_kernel(const float* __restrict__ x, const float* __restrict__ Wq,
                 const float* __restrict__ Wk, const float* __restrict__ Wv,
                 float* __restrict__ qp, float* __restrict__ kp, float* __restrict__ vp) {
  int t = blockIdx.x * 256 + threadIdx.x;
  int o = blockIdx.y;
  int n = blockIdx.z;
  const float* xn = x + (long)n * CDIM * TDIM;
  float aq = 0.f, ak = 0.f, av = 0.f;
  for (int c = 0; c < CDIM; ++c) {
    float xv = xn[c * TDIM + t];
    aq = fmaf(Wq[o * CDIM + c], xv, aq);
    ak = fmaf(Wk[o * CDIM + c], xv, ak);
    av = fmaf(Wv[o * CDIM + c], xv, av);
  }
  long idx = ((long)n * 256 + o) * TDIM + t;
  qp[idx] = aq; kp[idx] = ak; vp[idx] = av;
}

// ------------------------------------------------- circulant weights, transposed
__global__ __launch_bounds__(256)
void build_cpt_kernel(const float* __restrict__ w, ushort* __restrict__ cpt,
                      int outdim, int stride) {
  int i = blockIdx.x * 256 + threadIdx.x;
  int o  = i >> 10;
  int kk = i & 1023;
  int s = kk >> 1, r = kk & 1;
  float v = w[r * outdim + ((o - s * stride) & (outdim - 1))];
  cpt[i] = f2bf(v);
}

// ------------------------------------------------------------------- P0 build
__global__ __launch_bounds__(256)
void build_p0_kernel(const float* __restrict__ qp, const float* __restrict__ kp,
                     ushort* __restrict__ P) {
  int s = blockIdx.x * 256 + threadIdx.x;
  int t = blockIdx.y;
  int b = blockIdx.z;
  int n = b >> 3, h = b & 7;
  const float* qrow = qp + ((long)n * 256 + h * 32) * TDIM + t;
  const float* krow = kp + ((long)n * 256 + h * 32) * TDIM + s;
  float acc = 0.f;
#pragma unroll
  for (int d = 0; d < 32; ++d) acc = fmaf(qrow[d * TDIM], krow[d * TDIM], acc);
  acc *= 0.17677669529663687f;
  float pd = fabsf((float)(s - t)) * (1.0f / 511.0f);
  ushort2 pr; pr.x = f2bf(acc); pr.y = f2bf(pd);
  *(ushort2*)(P + (((long)b * TDIM + t) * T2 + 2 * s)) = pr;
}

// =================================================================== 256² GEMM
// Y[b] = A[b] (Mx1024, row-major) * BT[b] (ncols x 1024, row-major)^T
// 8-phase schedule (T2 swizzle + T3/T4 counted vmcnt + T5 setprio):
//   BM=BN=256, BK=64, 8 waves (2Mx4N), per-wave 128x64, LDS 128 KiB dbuf.
//   Per phase: ds_read quadrant frags | stage 1 half-tile (2 gload_lds) |
//   barrier | lgkmcnt(0) | setprio(1) 16xMFMA setprio(0) | barrier.
//   vmcnt(4) at phases 4 and 8 only (2 half-tiles kept in flight).
// LDS tile [256][64] bf16, 128-B rows, XOR-swizzle slot^=(row&7) (16B granule):
//   read conflict <= 2-way (free, m136). gload_lds dest is linear; source is
//   inverse-swizzled (rule #21).

#define LDS_BUF  65536   // bytes per buffer (A 32K + B 32K)
#define LDS_BOFF 32768   // B region offset within buffer

#define STAGE_A_(buf, h, kt) do { \
  const ushort* gA0_ = Ab + (long)((h)*128 +      sr0) * 1024 + (kt)*64 + slog8; \
  const ushort* gA1_ = Ab + (long)((h)*128 + 64 + sr0) * 1024 + (kt)*64 + slog8; \
  char* dA_ = ldsw + (size_t)(buf) * LDS_BUF + (h)*16384 + tid*16; \
  GLOAD_LDS16(gA0_, dA_); GLOAD_LDS16(gA1_, dA_ + 8192); } while(0)

#define STAGE_B_(buf, h, kt) do { \
  const ushort* gB0_ = Bb + (long)((h)*128 +      sr0) * 1024 + (kt)*64 + slog8; \
  const ushort* gB1_ = Bb + (long)((h)*128 + 64 + sr0) * 1024 + (kt)*64 + slog8; \
  char* dB_ = ldsw + (size_t)(buf) * LDS_BUF + LDS_BOFF + (h)*16384 + tid*16; \
  GLOAD_LDS16(gB0_, dB_); GLOAD_LDS16(gB1_, dB_ + 8192); } while(0)

#define LD_A_(buf, mh) do { \
  const char* aB_ = ldsc + (size_t)(buf) * LDS_BUF; \
  _Pragma("unroll") for (int mi = 0; mi < 4; ++mi) { \
    int ar_ = wm*128 + (mh)*64 + mi*16 + fr; \
    const char* rb_ = aB_ + ar_*128; int sw_ = (ar_&7)<<4; \
    af[mi][0] = *(const bf16x8*)(rb_ + ((fq*16) ^ sw_)); \
    af[mi][1] = *(const bf16x8*)(rb_ + ((64 + fq*16) ^ sw_)); \
  } } while(0)

#define LD_B_(dst, buf, nh) do { \
  const char* bB_ = ldsc + (size_t)(buf) * LDS_BUF + LDS_BOFF; \
  _Pragma("unroll") for (int ni = 0; ni < 2; ++ni) { \
    int br_ = wn*64 + (nh)*32 + ni*16 + fr; \
    const char* rb_ = bB_ + br_*128; int sw_ = (br_&7)<<4; \
    dst[ni][0] = *(const bf16x8*)(rb_ + ((fq*16) ^ sw_)); \
    dst[ni][1] = *(const bf16x8*)(rb_ + ((64 + fq*16) ^ sw_)); \
  } } while(0)

#define QUAD_(mh, nh, bfa) do { \
  __builtin_amdgcn_s_setprio(1); \
  _Pragma("unroll") for (int kk = 0; kk < 2; ++kk) \
  _Pragma("unroll") for (int mi = 0; mi < 4; ++mi) \
  _Pragma("unroll") for (int ni = 0; ni < 2; ++ni) \
    acc[(mh)*4+mi][(nh)*2+ni] = __builtin_amdgcn_mfma_f32_16x16x32_bf16( \
        af[mi][kk], bfa[ni][kk], acc[(mh)*4+mi][(nh)*2+ni], 0, 0, 0); \
  __builtin_amdgcn_s_setprio(0); } while(0)

template<bool FINAL>
__global__ __launch_bounds__(512, 2)
void gemm256_kernel(const ushort* __restrict__ A, long aStride,
                    const ushort* __restrict__ BT, long bStride,
                    void* __restrict__ Out, int ncols, float* __restrict__ stats) {
  __shared__ ushort lds[2][2][256 * 64];   // 128 KiB
  const int tid = threadIdx.x;
  const int bm = blockIdx.x, bn = blockIdx.y, b = blockIdx.z;
  const ushort* Ab = A  + (long)b * aStride + (long)bm * 256 * 1024;
  const ushort* Bb = BT + (long)b * bStride + (long)bn * 256 * 1024;
  const int lane = tid & 63;
  const int fr = lane & 15, fq = lane >> 4;
  const int wid = tid >> 6, wm = wid >> 2, wn = wid & 3;
  const int sr0 = tid >> 3;                  // staging row (load 0)
  const int slog8 = ((tid & 7) ^ (sr0 & 7)) * 8;  // inverse-swizzled source slot
  const char* ldsc = (const char*)&lds[0][0][0];
  char*       ldsw = (char*)&lds[0][0][0];

  f32x4 acc[8][4] = {};
  bf16x8 af[4][2], bf0[2][2], bf1[2][2];

  // Prologue: tile0 (buf0) fully, tile1 (buf1) B halves; tile1 A comes ph1/2.
  STAGE_B_(0, 0, 0); STAGE_B_(0, 1, 0);
  STAGE_A_(0, 0, 0); STAGE_A_(0, 1, 0);
  STAGE_B_(1, 0, 1); STAGE_B_(1, 1, 1);
  WAITV4();   // tile0's 8 loads done; tile1 B (4) in flight
  BAR();

  for (int i = 0; i < 8; ++i) {
    const int t1 = 2 * i + 1, t2 = 2 * i + 2, t3 = 2 * i + 3;
    const bool st = (i < 7);
    // ---- phases 1-4: compute tile 2i from buf0 ----
    LD_A_(0, 0); LD_B_(bf0, 0, 0);
    STAGE_A_(1, 0, t1);
    BAR(); WAITL(); QUAD_(0, 0, bf0); BAR();

    LD_B_(bf1, 0, 1);
    STAGE_A_(1, 1, t1);
    BAR(); WAITL(); QUAD_(0, 1, bf1); BAR();

    LD_A_(0, 1);
    if (st) STAGE_B_(0, 0, t2);
    BAR(); WAITL(); QUAD_(1, 1, bf1); BAR();

    if (st) { STAGE_B_(0, 1, t2); WAITV4(); } else { WAITV0(); }
    BAR(); QUAD_(1, 0, bf0); BAR();

    // ---- phases 5-8: compute tile 2i+1 from buf1 ----
    LD_A_(1, 0); LD_B_(bf0, 1, 0);
    if (st) STAGE_A_(0, 0, t2);
    BAR(); WAITL(); QUAD_(0, 0, bf0); BAR();

    LD_B_(bf1, 1, 1);
    if (st) STAGE_A_(0, 1, t2);
    BAR(); WAITL(); QUAD_(0, 1, bf1); BAR();

    LD_A_(1, 1);
    if (st) STAGE_B_(1, 0, t3);
    BAR(); WAITL(); QUAD_(1, 1, bf1); BAR();

    if (st) { STAGE_B_(1, 1, t3); WAITV4(); }
    BAR(); QUAD_(1, 0, bf0); BAR();
  }

  // ------------------------------------------------------------- epilogue
  const int r0 = bm * 256 + wm * 128;
  const int c0 = bn * 256 + wn * 64;
  if (!FINAL) {
    ushort* Yb = (ushort*)Out + (long)b * 512 * ncols;
    float s1 = 0.f, s2 = 0.f;
#pragma unroll
    for (int mi = 0; mi < 8; ++mi)
#pragma unroll
      for (int ni = 0; ni < 4; ++ni)
#pragma unroll
        for (int r = 0; r < 4; ++r) {
          float v = acc[mi][ni][r];
          s1 += v; s2 += v * v;
          int row = r0 + mi * 16 + fq * 4 + r;
          int col = c0 + ni * 16 + fr;
          Yb[(long)row * ncols + col] = f2bf(v);
        }
    __syncthreads();
    float* red = (float*)&lds[0][0][0];
    red[tid] = s1; red[tid + 512] = s2;
    __syncthreads();
    for (int off = 256; off > 0; off >>= 1) {
      if (tid < off) { red[tid] += red[tid + off]; red[512 + tid] += red[512 + tid + off]; }
      __syncthreads();
    }
    if (tid == 0) {
      atomicAdd(&stats[b * 2],     red[0]);
      atomicAdd(&stats[b * 2 + 1], red[512]);
    }
  } else {
    float* Lb = (float*)Out + (long)b * 512 * 512;
#pragma unroll
    for (int mi = 0; mi < 8; ++mi)
#pragma unroll
      for (int ni = 0; ni < 4; ++ni)
#pragma unroll
        for (int r = 0; r < 4; ++r) {
          int row = r0 + mi * 16 + fq * 4 + r;
          int col = c0 + ni * 16 + fr;
          Lb[(long)row * 512 + col] = acc[mi][ni][r];
        }
  }
}

// --------------------------------------------- LN + gelu + pair-transpose fused
__global__ __launch_bounds__(256)
void apply_kernel(const ushort* __restrict__ Y, const float* __restrict__ stats,
                  const float* __restrict__ g, const float* __restrict__ bia,
                  ushort* __restrict__ P) {
  __shared__ ushort2 tile[32][33];
  int ti = blockIdx.x;
  int si = blockIdx.y;
  int b  = blockIdx.z;
  float mu  = stats[b * 2] * (1.0f / MTOT);
  float var = stats[b * 2 + 1] * (1.0f / MTOT) - mu * mu;
  float rstd = rsqrtf(var + 1e-5f);
  int tx = threadIdx.x & 31, ty = threadIdx.x >> 5;
  const ushort* Yb = Y + (long)b * 512 * 1024;
#pragma unroll
  for (int i = 0; i < 4; ++i) {
    int t  = ti * 32 + ty + i * 8;
    int sp = si * 32 + tx;
    ushort2 yv = *(const ushort2*)(Yb + (long)t * 1024 + 2 * sp);
    float2 gv = *(const float2*)(g   + (long)t * 1024 + 2 * sp);
    float2 bv = *(const float2*)(bia + (long)t * 1024 + 2 * sp);
    float y0 = (bf2f(yv.x) - mu) * rstd * gv.x + bv.x;
    float y1 = (bf2f(yv.y) - mu) * rstd * gv.y + bv.y;
    ushort2 o; o.x = f2bf(gelu_exact(y0)); o.y = f2bf(gelu_exact(y1));
    tile[ty + i * 8][tx] = o;
  }
  __syncthreads();
  ushort* Pb = P + (long)b * 512 * 1024;
#pragma unroll
  for (int i = 0; i < 4; ++i) {
    int srow = si * 32 + ty + i * 8;
    int tcol = ti * 32 + tx;
    ushort2 v = tile[tx][ty + i * 8];
    *(ushort2*)(Pb + (long)srow * 1024 + 2 * tcol) = v;
  }
}

// ------------------------------------------------------------------- softmax
__global__ __launch_bounds__(256)
void softmax_kernel(float* __restrict__ L) {
  int wid = threadIdx.x >> 6, lane = threadIdx.x & 63;
  long row = (long)blockIdx.x * 4 + wid;
  float* Lr = L + row * 512;
  float4 a = *(float4*)(Lr + lane * 8);
  float4 c = *(float4*)(Lr + lane * 8 + 4);
  float m = fmaxf(fmaxf(fmaxf(a.x, a.y), fmaxf(a.z, a.w)),
                  fmaxf(fmaxf(c.x, c.y), fmaxf(c.z, c.w)));
  for (int off = 32; off > 0; off >>= 1) m = fmaxf(m, __shfl_xor(m, off, 64));
  a.x = expf(a.x - m); a.y = expf(a.y - m); a.z = expf(a.z - m); a.w = expf(a.w - m);
  c.x = expf(c.x - m); c.y = expf(c.y - m); c.z = expf(c.z - m); c.w = expf(c.w - m);
  float s = a.x + a.y + a.z + a.w + c.x + c.y + c.z + c.w;
  for (int off = 32; off > 0; off >>= 1) s += __shfl_xor(s, off, 64);
  float inv = 1.0f / s;
  a.x *= inv; a.y *= inv; a.z *= inv; a.w *= inv;
  c.x *= inv; c.y *= inv; c.z *= inv; c.w *= inv;
  *(float4*)(Lr + lane * 8) = a;
  *(float4*)(Lr + lane * 8 + 4) = c;
}

// ------------------------------------------------------------------ attn @ V
__global__ __launch_bounds__(256)
void av_kernel(const float* __restrict__ L, const float* __restrict__ vp,
               float* __restrict__ out) {
  __shared__ float vt[32 * 512];
  int bh = blockIdx.x;
  int at = blockIdx.y;
  int n = bh >> 3, h = bh & 7;
  const float* vsrc = vp + ((long)n * 256 + h * 32) * 512;
  for (int i = threadIdx.x; i < 32 * 512 / 4; i += 256)
    ((float4*)vt)[i] = ((const float4*)vsrc)[i];
  __syncthreads();
  int a  = at * 32 + (threadIdx.x & 31);
  int d0 = (threadIdx.x >> 5) * 4;
  const float* Lr = L + ((long)bh * 512 + a) * 512;
  float acc0 = 0.f, acc1 = 0.f, acc2 = 0.f, acc3 = 0.f;
  for (int bcol = 0; bcol < 512; ++bcol) {
    float p = Lr[bcol];
    acc0 = fmaf(p, vt[(d0 + 0) * 512 + bcol], acc0);
    acc1 = fmaf(p, vt[(d0 + 1) * 512 + bcol], acc1);
    acc2 = fmaf(p, vt[(d0 + 2) * 512 + bcol], acc2);
    acc3 = fmaf(p, vt[(d0 + 3) * 512 + bcol], acc3);
  }
  float* ob = out + ((long)n * 256 + h * 32) * 512;
  ob[(d0 + 0) * 512 + a] = acc0;
  ob[(d0 + 1) * 512 + a] = acc1;
  ob[(d0 + 2) * 512 + a] = acc2;
  ob[(d0 + 3) * 512 + a] = acc3;
}

// -------------------------------------------------------------------- launch
extern "C" void kernel_launch(void* const* d_in, const int* in_sizes, int n_in,
                              void* d_out, int out_size, void* d_ws, size_t ws_size,
                              hipStream_t stream) {
  const float* x     = (const float*)d_in[0];
  const float* Wq    = (const float*)d_in[1];
  const float* Wk    = (const float*)d_in[2];
  const float* Wv    = (const float*)d_in[3];
  const float* m1w0  = (const float*)d_in[4];
  const float* m2w0  = (const float*)d_in[5];
  const float* m1w1  = (const float*)d_in[6];
  const float* m2w1  = (const float*)d_in[7];
  const float* ln1g0 = (const float*)d_in[8];
  const float* ln1b0 = (const float*)d_in[9];
  const float* ln2g0 = (const float*)d_in[10];
  const float* ln2b0 = (const float*)d_in[11];
  const float* ln1g1 = (const float*)d_in[12];
  const float* ln1b1 = (const float*)d_in[13];

  char* w = (char*)d_ws;
  float*  qp    = (float*) (w + 0);
  float*  kp    = (float*) (w + (4ull  << 20));
  float*  vp    = (float*) (w + (8ull  << 20));
  float*  stats = (float*) (w + (12ull << 20));
  ushort* cpt0  = (ushort*)(w + (13ull << 20));
  ushort* cpt1  = (ushort*)(w + (15ull << 20));
  ushort* cpt2  = (ushort*)(w + (17ull << 20));
  ushort* cpt3  = (ushort*)(w + (19ull << 20));
  ushort* bufA  = (ushort*)(w + (20ull << 20));
  ushort* bufB  = (ushort*)(w + (84ull << 20));
  float*  L     = (float*)bufB;
  float*  outp  = (float*)d_out;

  hipMemsetAsync(stats, 0, 3 * NB * 2 * sizeof(float), stream);

  proj_kernel<<<dim3(2, 256, 8), 256, 0, stream>>>(x, Wq, Wk, Wv, qp, kp, vp);
  build_cpt_kernel<<<4096, 256, 0, stream>>>(m1w0, cpt0, 1024, 2);
  build_cpt_kernel<<<4096, 256, 0, stream>>>(m2w0, cpt1, 1024, 2);
  build_cpt_kernel<<<4096, 256, 0, stream>>>(m1w1, cpt2, 1024, 2);
  build_cpt_kernel<<<2048, 256, 0, stream>>>(m2w1, cpt3, 512, 1);
  build_p0_kernel<<<dim3(2, 512, 64), 256, 0, stream>>>(qp, kp, bufA);

  gemm256_kernel<false><<<dim3(2, 4, 64), 512, 0, stream>>>(bufA, 512L * 1024, cpt0, 0, bufB, 1024, stats);
  apply_kernel<<<dim3(16, 16, 64), 256, 0, stream>>>(bufB, stats, ln1g0, ln1b0, bufA);
  gemm256_kernel<false><<<dim3(2, 4, 64), 512, 0, stream>>>(bufA, 512L * 1024, cpt1, 0, bufB, 1024, stats + 128);
  apply_kernel<<<dim3(16, 16, 64), 256, 0, stream>>>(bufB, stats + 128, ln2g0, ln2b0, bufA);
  gemm256_kernel<false><<<dim3(2, 4, 64), 512, 0, stream>>>(bufA, 512L * 1024, cpt2, 0, bufB, 1024, stats + 256);
  apply_kernel<<<dim3(16, 16, 64), 256, 0, stream>>>(bufB, stats + 256, ln1g1, ln1b1, bufA);
  gemm256_kernel<true><<<dim3(2, 2, 64), 512, 0, stream>>>(cpt3, 0, bufA, 512L * 1024, L, 512, nullptr);
  softmax_kernel<<<8192, 256, 0, stream>>>(L);
  av_kernel<<<dim3(64, 16), 256, 0, stream>>>(L, vp, outp);
}

// Round 3
// 528.128 us; speedup vs baseline: 1.2345x; 1.0640x over previous
//
#include <hip/hip_runtime.h>
#include <hip/hip_bf16.h>
#include <math.h>

// Problem constants
#define CDIM 256
#define TDIM 512
#define T2   1024
#define NB   64      // N*H batches
#define MTOT 524288.0f   // T*2T elements per batch for LN

typedef __bf16 bf16x8 __attribute__((ext_vector_type(8)));
typedef float  f32x4  __attribute__((ext_vector_type(4)));

__device__ __forceinline__ ushort f2bf(float f) {
  union { float f; unsigned u; } v; v.f = f;
  unsigned r = v.u + 0x7fffu + ((v.u >> 16) & 1u);
  return (ushort)(r >> 16);
}
__device__ __forceinline__ float bf2f(ushort h) {
  union { unsigned u; float f; } v; v.u = ((unsigned)h) << 16;
  return v.f;
}
__device__ __forceinline__ float gelu_exact(float x) {
  return 0.5f * x * (1.0f + erff(x * 0.7071067811865475f));
}

#define TO_LDS(p)  ((__attribute__((address_space(3))) void*)(unsigned)(uintptr_t)(p))
#define TO_GLB(p)  ((const __attribute__((address_space(1))) void*)(uintptr_t)(p))
#define GLOAD_LDS16(g, l) __builtin_amdgcn_global_load_lds(TO_GLB(g), TO_LDS(l), 16, 0, 0)

#define BAR()    asm volatile("s_barrier" ::: "memory")
#define WAITL()  asm volatile("s_waitcnt lgkmcnt(0)" ::: "memory")
#define WAITV4() asm volatile("s_waitcnt vmcnt(4)" ::: "memory")
#define WAITV0() asm volatile("s_waitcnt vmcnt(0)" ::: "memory")

// ---------------------------------------------------------------- projections
// qb/kb: bf16 [b=n*8+h][t][d(32)]  (MFMA-ready, 64B rows); vp: f32 [n][o][t]
__global__ __launch_bounds__(256)
void proj_kernel(const float* __restrict__ x, const float* __restrict__ Wq,
                 const float* __restrict__ Wk, const float* __restrict__ Wv,
                 ushort* __restrict__ qb, ushort* __restrict__ kb,
                 float* __restrict__ vp) {
  int t = blockIdx.x * 256 + threadIdx.x;
  int o = blockIdx.y;
  int n = blockIdx.z;
  const float* xn = x + (long)n * CDIM * TDIM;
  float aq = 0.f, ak = 0.f, av = 0.f;
  for (int c = 0; c < CDIM; ++c) {
    float xv = xn[c * TDIM + t];
    aq = fmaf(Wq[o * CDIM + c], xv, aq);
    ak = fmaf(Wk[o * CDIM + c], xv, ak);
    av = fmaf(Wv[o * CDIM + c], xv, av);
  }
  int h = o >> 5, d = o & 31;
  long bidx = (((long)(n * 8 + h) * 512) + t) * 32 + d;
  qb[bidx] = f2bf(aq);
  kb[bidx] = f2bf(ak);
  vp[((long)n * 256 + o) * TDIM + t] = av;
}

// ---------------------------------------- all small precompute in one kernel
// cpte0[o][s]=w10[0][(o-2s)%1024], cpto0[o][s]=w10[1][(o-2s)%1024]  (o<1024,s<512)
// cpt1/cpt2[o][kk]=w[kk&1][(o-2(kk>>1))%1024]                        (o<1024,kk<1024)
// cpt3[o][kk]=w21[kk&1][(o-(kk>>1))%512]                             (o<512, kk<1024)
// pdb[t][s]=|s-t|/511                                                (t,s<512)
__global__ __launch_bounds__(256)
void prep_kernel(const float* __restrict__ m1w0, const float* __restrict__ m2w0,
                 const float* __restrict__ m1w1, const float* __restrict__ m2w1,
                 ushort* __restrict__ cpte0, ushort* __restrict__ cpto0,
                 ushort* __restrict__ cpt1, ushort* __restrict__ cpt2,
                 ushort* __restrict__ cpt3, ushort* __restrict__ pdb) {
  long i = (long)blockIdx.x * 256 + threadIdx.x;
  if (i < 524288) {                 // cpte0 + cpto0
    int o = (int)(i >> 9), s = (int)(i & 511);
    int idx = (o - 2 * s) & 1023;
    cpte0[i] = f2bf(m1w0[idx]);
    cpto0[i] = f2bf(m1w0[1024 + idx]);
  } else if (i < 1572864) {         // cpt1
    long j = i - 524288;
    int o = (int)(j >> 10), kk = (int)(j & 1023);
    cpt1[j] = f2bf(m2w0[(kk & 1) * 1024 + ((o - 2 * (kk >> 1)) & 1023)]);
  } else if (i < 2621440) {         // cpt2
    long j = i - 1572864;
    int o = (int)(j >> 10), kk = (int)(j & 1023);
    cpt2[j] = f2bf(m1w1[(kk & 1) * 1024 + ((o - 2 * (kk >> 1)) & 1023)]);
  } else if (i < 3145728) {         // cpt3
    long j = i - 2621440;
    int o = (int)(j >> 10), kk = (int)(j & 1023);
    cpt3[j] = f2bf(m2w1[(kk & 1) * 512 + ((o - (kk >> 1)) & 511)]);
  } else if (i < 3407872) {         // pdb
    long j = i - 3145728;
    int t = (int)(j >> 9), s = (int)(j & 511);
    pdb[j] = f2bf(fabsf((float)(s - t)) * (1.0f / 511.0f));
  }
}

// ------------------------------------------------------------ MFMA QK^T scores
// S[b][t][s] = (q.k)/sqrt(32), bf16.  One 16x16x32 MFMA per tile (K=dk=32).
__global__ __launch_bounds__(256)
void scores_kernel(const ushort* __restrict__ qb, const ushort* __restrict__ kb,
                   ushort* __restrict__ S) {
  int tb = blockIdx.x;              // 8 t-blocks of 64
  int b  = blockIdx.y;              // 64
  int wv = threadIdx.x >> 6, lane = threadIdx.x & 63;
  int fr = lane & 15, fq = lane >> 4;
  int t0 = tb * 64 + wv * 16;
  bf16x8 af = *(const bf16x8*)(qb + ((long)b * 512 + t0 + fr) * 32 + fq * 8);
  const ushort* kbase = kb + (long)b * 512 * 32 + fr * 32 + fq * 8;
  ushort* Sb = S + ((long)b * 512 + t0 + fq * 4) * 512 + fr;
  f32x4 zz = {0.f, 0.f, 0.f, 0.f};
#pragma unroll 4
  for (int st = 0; st < 32; ++st) {
    bf16x8 bfv = *(const bf16x8*)(kbase + st * 512);
    f32x4 acc = __builtin_amdgcn_mfma_f32_16x16x32_bf16(af, bfv, zz, 0, 0, 0);
#pragma unroll
    for (int r = 0; r < 4; ++r)
      Sb[(long)r * 512 + st * 16] = f2bf(acc[r] * 0.17677669529663687f);
  }
}

// =================================================================== 256² GEMM
// Y[b] = A[b] (M x K, row-major) * BT[b] (ncols x K, row-major)^T  [+ Cadd]
// 8-phase schedule (T2 swizzle + T3/T4 counted vmcnt + T5 setprio).
#define LDS_BUF  65536
#define LDS_BOFF 32768

#define STAGE_A_(buf, h, kt) do { \
  const ushort* gA0_ = Ab + (long)((h)*128 +      sr0) * Krow + (kt)*64 + slog8; \
  const ushort* gA1_ = Ab + (long)((h)*128 + 64 + sr0) * Krow + (kt)*64 + slog8; \
  char* dA_ = ldsw + (size_t)(buf) * LDS_BUF + (h)*16384 + tid*16; \
  GLOAD_LDS16(gA0_, dA_); GLOAD_LDS16(gA1_, dA_ + 8192); } while(0)

#define STAGE_B_(buf, h, kt) do { \
  const ushort* gB0_ = Bb + (long)((h)*128 +      sr0) * Krow + (kt)*64 + slog8; \
  const ushort* gB1_ = Bb + (long)((h)*128 + 64 + sr0) * Krow + (kt)*64 + slog8; \
  char* dB_ = ldsw + (size_t)(buf) * LDS_BUF + LDS_BOFF + (h)*16384 + tid*16; \
  GLOAD_LDS16(gB0_, dB_); GLOAD_LDS16(gB1_, dB_ + 8192); } while(0)

#define LD_A_(buf, mh) do { \
  const char* aB_ = ldsc + (size_t)(buf) * LDS_BUF; \
  _Pragma("unroll") for (int mi = 0; mi < 4; ++mi) { \
    int ar_ = wm*128 + (mh)*64 + mi*16 + fr; \
    const char* rb_ = aB_ + ar_*128; int sw_ = (ar_&7)<<4; \
    af[mi][0] = *(const bf16x8*)(rb_ + ((fq*16) ^ sw_)); \
    af[mi][1] = *(const bf16x8*)(rb_ + ((64 + fq*16) ^ sw_)); \
  } } while(0)

#define LD_B_(dst, buf, nh) do { \
  const char* bB_ = ldsc + (size_t)(buf) * LDS_BUF + LDS_BOFF; \
  _Pragma("unroll") for (int ni = 0; ni < 2; ++ni) { \
    int br_ = wn*64 + (nh)*32 + ni*16 + fr; \
    const char* rb_ = bB_ + br_*128; int sw_ = (br_&7)<<4; \
    dst[ni][0] = *(const bf16x8*)(rb_ + ((fq*16) ^ sw_)); \
    dst[ni][1] = *(const bf16x8*)(rb_ + ((64 + fq*16) ^ sw_)); \
  } } while(0)

#define QUAD_(mh, nh, bfa) do { \
  __builtin_amdgcn_s_setprio(1); \
  _Pragma("unroll") for (int kk = 0; kk < 2; ++kk) \
  _Pragma("unroll") for (int mi = 0; mi < 4; ++mi) \
  _Pragma("unroll") for (int ni = 0; ni < 2; ++ni) \
    acc[(mh)*4+mi][(nh)*2+ni] = __builtin_amdgcn_mfma_f32_16x16x32_bf16( \
        af[mi][kk], bfa[ni][kk], acc[(mh)*4+mi][(nh)*2+ni], 0, 0, 0); \
  __builtin_amdgcn_s_setprio(0); } while(0)

template<bool FINAL>
__global__ __launch_bounds__(512, 2)
void gemm256_kernel(const ushort* __restrict__ A, long aStride,
                    const ushort* __restrict__ BT, long bStride,
                    void* __restrict__ Out, int ncols, float* __restrict__ stats,
                    const float* __restrict__ Cadd, int K) {
  __shared__ ushort lds[2][2][256 * 64];   // 128 KiB
  const int tid = threadIdx.x;
  const int bm = blockIdx.x, bn = blockIdx.y, b = blockIdx.z;
  const int Krow = K;
  const int nkt2 = K >> 7;
  const ushort* Ab = A  + (long)b * aStride + (long)bm * 256 * Krow;
  const ushort* Bb = BT + (long)b * bStride + (long)bn * 256 * Krow;
  const int lane = tid & 63;
  const int fr = lane & 15, fq = lane >> 4;
  const int wid = tid >> 6, wm = wid >> 2, wn = wid & 3;
  const int sr0 = tid >> 3;
  const int slog8 = ((tid & 7) ^ (sr0 & 7)) * 8;
  const char* ldsc = (const char*)&lds[0][0][0];
  char*       ldsw = (char*)&lds[0][0][0];

  f32x4 acc[8][4] = {};
  bf16x8 af[4][2], bf0[2][2], bf1[2][2];

  STAGE_B_(0, 0, 0); STAGE_B_(0, 1, 0);
  STAGE_A_(0, 0, 0); STAGE_A_(0, 1, 0);
  STAGE_B_(1, 0, 1); STAGE_B_(1, 1, 1);
  WAITV4();
  BAR();

  for (int i = 0; i < nkt2; ++i) {
    const int t1 = 2 * i + 1, t2 = 2 * i + 2, t3 = 2 * i + 3;
    const bool st = (i < nkt2 - 1);
    LD_A_(0, 0); LD_B_(bf0, 0, 0);
    STAGE_A_(1, 0, t1);
    BAR(); WAITL(); QUAD_(0, 0, bf0); BAR();

    LD_B_(bf1, 0, 1);
    STAGE_A_(1, 1, t1);
    BAR(); WAITL(); QUAD_(0, 1, bf1); BAR();

    LD_A_(0, 1);
    if (st) STAGE_B_(0, 0, t2);
    BAR(); WAITL(); QUAD_(1, 1, bf1); BAR();

    if (st) { STAGE_B_(0, 1, t2); WAITV4(); } else { WAITV0(); }
    BAR(); QUAD_(1, 0, bf0); BAR();

    LD_A_(1, 0); LD_B_(bf0, 1, 0);
    if (st) STAGE_A_(0, 0, t2);
    BAR(); WAITL(); QUAD_(0, 0, bf0); BAR();

    LD_B_(bf1, 1, 1);
    if (st) STAGE_A_(0, 1, t2);
    BAR(); WAITL(); QUAD_(0, 1, bf1); BAR();

    LD_A_(1, 1);
    if (st) STAGE_B_(1, 0, t3);
    BAR(); WAITL(); QUAD_(1, 1, bf1); BAR();

    if (st) { STAGE_B_(1, 1, t3); WAITV4(); }
    BAR(); QUAD_(1, 0, bf0); BAR();
  }

  const int r0 = bm * 256 + wm * 128;
  const int c0 = bn * 256 + wn * 64;
  if (!FINAL) {
    ushort* Yb = (ushort*)Out + (long)b * 512 * ncols;
    float s1 = 0.f, s2 = 0.f;
#pragma unroll
    for (int mi = 0; mi < 8; ++mi)
#pragma unroll
      for (int ni = 0; ni < 4; ++ni)
#pragma unroll
        for (int r = 0; r < 4; ++r) {
          float v = acc[mi][ni][r];
          int row = r0 + mi * 16 + fq * 4 + r;
          int col = c0 + ni * 16 + fr;
          if (Cadd) v += Cadd[(long)row * ncols + col];
          s1 += v; s2 += v * v;
          Yb[(long)row * ncols + col] = f2bf(v);
        }
    __syncthreads();
    float* red = (float*)&lds[0][0][0];
    red[tid] = s1; red[tid + 512] = s2;
    __syncthreads();
    for (int off = 256; off > 0; off >>= 1) {
      if (tid < off) { red[tid] += red[tid + off]; red[512 + tid] += red[512 + tid + off]; }
      __syncthreads();
    }
    if (tid == 0) {
      atomicAdd(&stats[b * 2],     red[0]);
      atomicAdd(&stats[b * 2 + 1], red[512]);
    }
  } else {
    float* Lb = (float*)Out + (long)b * 512 * ncols;
#pragma unroll
    for (int mi = 0; mi < 8; ++mi)
#pragma unroll
      for (int ni = 0; ni < 4; ++ni)
#pragma unroll
        for (int r = 0; r < 4; ++r) {
          int row = r0 + mi * 16 + fq * 4 + r;
          int col = c0 + ni * 16 + fr;
          Lb[(long)row * ncols + col] = acc[mi][ni][r];
        }
  }
}

// --------------------------------------------- LN + gelu + pair-transpose fused
__global__ __launch_bounds__(256)
void apply_kernel(const ushort* __restrict__ Y, const float* __restrict__ stats,
                  const float* __restrict__ g, const float* __restrict__ bia,
                  ushort* __restrict__ P) {
  __shared__ ushort2 tile[32][33];
  int ti = blockIdx.x;
  int si = blockIdx.y;
  int b  = blockIdx.z;
  float mu  = stats[b * 2] * (1.0f / MTOT);
  float var = stats[b * 2 + 1] * (1.0f / MTOT) - mu * mu;
  float rstd = rsqrtf(var + 1e-5f);
  int tx = threadIdx.x & 31, ty = threadIdx.x >> 5;
  const ushort* Yb = Y + (long)b * 512 * 1024;
#pragma unroll
  for (int i = 0; i < 4; ++i) {
    int t  = ti * 32 + ty + i * 8;
    int sp = si * 32 + tx;
    ushort2 yv = *(const ushort2*)(Yb + (long)t * 1024 + 2 * sp);
    float2 gv = *(const float2*)(g   + (long)t * 1024 + 2 * sp);
    float2 bv = *(const float2*)(bia + (long)t * 1024 + 2 * sp);
    float y0 = (bf2f(yv.x) - mu) * rstd * gv.x + bv.x;
    float y1 = (bf2f(yv.y) - mu) * rstd * gv.y + bv.y;
    ushort2 o; o.x = f2bf(gelu_exact(y0)); o.y = f2bf(gelu_exact(y1));
    tile[ty + i * 8][tx] = o;
  }
  __syncthreads();
  ushort* Pb = P + (long)b * 512 * 1024;
#pragma unroll
  for (int i = 0; i < 4; ++i) {
    int srow = si * 32 + ty + i * 8;
    int tcol = ti * 32 + tx;
    ushort2 v = tile[tx][ty + i * 8];
    *(ushort2*)(Pb + (long)srow * 1024 + 2 * tcol) = v;
  }
}

// ----------------------------------------------------- fused softmax + attn@V
// Step1: softmax L rows (wave-per-row) into LDS. Step2: out = attn @ V.
__global__ __launch_bounds__(256)
void smax_av_kernel(const float* __restrict__ L, const float* __restrict__ vp,
                    float* __restrict__ out) {
  __shared__ float Lt[32][513];
  int bh = blockIdx.x;   // 64
  int at = blockIdx.y;   // 16 tiles of 32 rows
  int n = bh >> 3, h = bh & 7;
  int wv = threadIdx.x >> 6, lane = threadIdx.x & 63;
  for (int rr = 0; rr < 8; ++rr) {
    int row = wv * 8 + rr;
    int a = at * 32 + row;
    const float* Lr = L + ((long)bh * 512 + a) * 512;
    float e[8];
#pragma unroll
    for (int j = 0; j < 8; ++j) e[j] = Lr[j * 64 + lane];
    float m = e[0];
#pragma unroll
    for (int j = 1; j < 8; ++j) m = fmaxf(m, e[j]);
    for (int off = 32; off > 0; off >>= 1) m = fmaxf(m, __shfl_xor(m, off, 64));
    float s = 0.f;
#pragma unroll
    for (int j = 0; j < 8; ++j) { e[j] = expf(e[j] - m); s += e[j]; }
    for (int off = 32; off > 0; off >>= 1) s += __shfl_xor(s, off, 64);
    float inv = 1.0f / s;
#pragma unroll
    for (int j = 0; j < 8; ++j) Lt[row][j * 64 + lane] = e[j] * inv;
  }
  __syncthreads();
  int r  = threadIdx.x & 31;
  int d0 = (threadIdx.x >> 5) * 4;
  const float* vb = vp + ((long)n * 256 + h * 32) * 512;
  float a0 = 0.f, a1 = 0.f, a2 = 0.f, a3 = 0.f;
  for (int bc = 0; bc < 512; bc += 4) {
    float4 v0 = *(const float4*)(vb + (d0 + 0) * 512 + bc);
    float4 v1 = *(const float4*)(vb + (d0 + 1) * 512 + bc);
    float4 v2 = *(const float4*)(vb + (d0 + 2) * 512 + bc);
    float4 v3 = *(const float4*)(vb + (d0 + 3) * 512 + bc);
    float p0 = Lt[r][bc], p1 = Lt[r][bc + 1], p2 = Lt[r][bc + 2], p3 = Lt[r][bc + 3];
    a0 = fmaf(p0, v0.x, fmaf(p1, v0.y, fmaf(p2, v0.z, fmaf(p3, v0.w, a0))));
    a1 = fmaf(p0, v1.x, fmaf(p1, v1.y, fmaf(p2, v1.z, fmaf(p3, v1.w, a1))));
    a2 = fmaf(p0, v2.x, fmaf(p1, v2.y, fmaf(p2, v2.z, fmaf(p3, v2.w, a2))));
    a3 = fmaf(p0, v3.x, fmaf(p1, v3.y, fmaf(p2, v3.z, fmaf(p3, v3.w, a3))));
  }
  int a = at * 32 + r;
  float* ob = out + ((long)n * 256 + h * 32) * 512;
  ob[(d0 + 0) * 512 + a] = a0;
  ob[(d0 + 1) * 512 + a] = a1;
  ob[(d0 + 2) * 512 + a] = a2;
  ob[(d0 + 3) * 512 + a] = a3;
}

// -------------------------------------------------------------------- launch
extern "C" void kernel_launch(void* const* d_in, const int* in_sizes, int n_in,
                              void* d_out, int out_size, void* d_ws, size_t ws_size,
                              hipStream_t stream) {
  const float* x     = (const float*)d_in[0];
  const float* Wq    = (const float*)d_in[1];
  const float* Wk    = (const float*)d_in[2];
  const float* Wv    = (const float*)d_in[3];
  const float* m1w0  = (const float*)d_in[4];
  const float* m2w0  = (const float*)d_in[5];
  const float* m1w1  = (const float*)d_in[6];
  const float* m2w1  = (const float*)d_in[7];
  const float* ln1g0 = (const float*)d_in[8];
  const float* ln1b0 = (const float*)d_in[9];
  const float* ln2g0 = (const float*)d_in[10];
  const float* ln2b0 = (const float*)d_in[11];
  const float* ln1g1 = (const float*)d_in[12];
  const float* ln1b1 = (const float*)d_in[13];

  char* w = (char*)d_ws;
  float*  vp     = (float*) (w + 0);                 // 4 MB
  ushort* qb     = (ushort*)(w + (4ull  << 20));     // 2 MB
  ushort* kb     = (ushort*)(w + (6ull  << 20));     // 2 MB
  float*  stats  = (float*) (w + (8ull  << 20));     // small
  ushort* cpte0  = (ushort*)(w + (9ull  << 20));     // 1 MB
  ushort* cpto0  = (ushort*)(w + (10ull << 20));     // 1 MB
  ushort* cpt1   = (ushort*)(w + (11ull << 20));     // 2 MB
  ushort* cpt2   = (ushort*)(w + (13ull << 20));     // 2 MB
  ushort* cpt3   = (ushort*)(w + (15ull << 20));     // 1 MB
  ushort* pdb    = (ushort*)(w + (16ull << 20));     // 0.5 MB
  float*  pdpart = (float*) (w + (17ull << 20));     // 2 MB
  ushort* bufA   = (ushort*)(w + (20ull << 20));     // 64 MB (S in first 32 MB)
  ushort* bufB   = (ushort*)(w + (84ull << 20));     // 64 MB (also L as f32)
  ushort* S      = bufA;
  float*  L      = (float*)bufB;
  float*  outp   = (float*)d_out;

  hipMemsetAsync(stats, 0, 3 * NB * 2 * sizeof(float), stream);

  proj_kernel<<<dim3(2, 256, 8), 256, 0, stream>>>(x, Wq, Wk, Wv, qb, kb, vp);
  prep_kernel<<<13312, 256, 0, stream>>>(m1w0, m2w0, m1w1, m2w1,
                                         cpte0, cpto0, cpt1, cpt2, cpt3, pdb);
  scores_kernel<<<dim3(8, 64), 256, 0, stream>>>(qb, kb, S);
  // pd_part[t][o] = sum_s pdb[t,s] * cpto0[o,s]   (batch-independent)
  gemm256_kernel<true><<<dim3(2, 4, 1), 512, 0, stream>>>(
      pdb, 0, cpto0, 0, pdpart, 1024, nullptr, nullptr, 512);
  // Y1 = S @ cpte0^T + pd_part
  gemm256_kernel<false><<<dim3(2, 4, 64), 512, 0, stream>>>(
      S, 512L * 512, cpte0, 0, bufB, 1024, stats, pdpart, 512);
  apply_kernel<<<dim3(16, 16, 64), 256, 0, stream>>>(bufB, stats, ln1g0, ln1b0, bufA);
  gemm256_kernel<false><<<dim3(2, 4, 64), 512, 0, stream>>>(
      bufA, 512L * 1024, cpt1, 0, bufB, 1024, stats + 128, nullptr, 1024);
  apply_kernel<<<dim3(16, 16, 64), 256, 0, stream>>>(bufB, stats + 128, ln2g0, ln2b0, bufA);
  gemm256_kernel<false><<<dim3(2, 4, 64), 512, 0, stream>>>(
      bufA, 512L * 1024, cpt2, 0, bufB, 1024, stats + 256, nullptr, 1024);
  apply_kernel<<<dim3(16, 16, 64), 256, 0, stream>>>(bufB, stats + 256, ln1g1, ln1b1, bufA);
  // L[b, a, t] = sum_k cpt3[a,k] * P3'[t,k]   (softmax-ready layout)
  gemm256_kernel<true><<<dim3(2, 2, 64), 512, 0, stream>>>(
      cpt3, 0, bufA, 512L * 1024, L, 512, nullptr, nullptr, 1024);
  smax_av_kernel<<<dim3(64, 16), 256, 0, stream>>>(L, vp, outp);
}

// Round 5
// 516.285 us; speedup vs baseline: 1.2628x; 1.0229x over previous
//
#include <hip/hip_runtime.h>
#include <hip/hip_bf16.h>
#include <math.h>

// Problem constants
#define CDIM 256
#define TDIM 512
#define T2   1024
#define NB   64      // N*H batches
#define MTOT 524288.0f   // T*2T elements per batch for LN

typedef __bf16 bf16x8 __attribute__((ext_vector_type(8)));
typedef float  f32x4  __attribute__((ext_vector_type(4)));

__device__ __forceinline__ ushort f2bf(float f) {
  union { float f; unsigned u; } v; v.f = f;
  unsigned r = v.u + 0x7fffu + ((v.u >> 16) & 1u);
  return (ushort)(r >> 16);
}
__device__ __forceinline__ float bf2f(ushort h) {
  union { unsigned u; float f; } v; v.u = ((unsigned)h) << 16;
  return v.f;
}
__device__ __forceinline__ float gelu_exact(float x) {
  return 0.5f * x * (1.0f + erff(x * 0.7071067811865475f));
}

#define TO_LDS(p)  ((__attribute__((address_space(3))) void*)(unsigned)(uintptr_t)(p))
#define TO_GLB(p)  ((const __attribute__((address_space(1))) void*)(uintptr_t)(p))
#define GLOAD_LDS16(g, l) __builtin_amdgcn_global_load_lds(TO_GLB(g), TO_LDS(l), 16, 0, 0)

#define BAR()    asm volatile("s_barrier" ::: "memory")
#define WAITL()  asm volatile("s_waitcnt lgkmcnt(0)" ::: "memory")
#define WAITV4() asm volatile("s_waitcnt vmcnt(4)" ::: "memory")
#define WAITV0() asm volatile("s_waitcnt vmcnt(0)" ::: "memory")

// ---------------------------------------------------------------- projections
// qb/kb: bf16 [b=n*8+h][t][d(32)]  (MFMA-ready, 64B rows); vp: f32 [n][o][t]
__global__ __launch_bounds__(256)
void proj_kernel(const float* __restrict__ x, const float* __restrict__ Wq,
                 const float* __restrict__ Wk, const float* __restrict__ Wv,
                 ushort* __restrict__ qb, ushort* __restrict__ kb,
                 float* __restrict__ vp) {
  int t = blockIdx.x * 256 + threadIdx.x;
  int o = blockIdx.y;
  int n = blockIdx.z;
  const float* xn = x + (long)n * CDIM * TDIM;
  float aq = 0.f, ak = 0.f, av = 0.f;
  for (int c = 0; c < CDIM; ++c) {
    float xv = xn[c * TDIM + t];
    aq = fmaf(Wq[o * CDIM + c], xv, aq);
    ak = fmaf(Wk[o * CDIM + c], xv, ak);
    av = fmaf(Wv[o * CDIM + c], xv, av);
  }
  int h = o >> 5, d = o & 31;
  long bidx = (((long)(n * 8 + h) * 512) + t) * 32 + d;
  qb[bidx] = f2bf(aq);
  kb[bidx] = f2bf(ak);
  vp[((long)n * 256 + o) * TDIM + t] = av;
}

// ---------------------------------------- all small precompute in one kernel
__global__ __launch_bounds__(256)
void prep_kernel(const float* __restrict__ m1w0, const float* __restrict__ m2w0,
                 const float* __restrict__ m1w1, const float* __restrict__ m2w1,
                 ushort* __restrict__ cpte0, ushort* __restrict__ cpto0,
                 ushort* __restrict__ cpt1, ushort* __restrict__ cpt2,
                 ushort* __restrict__ cpt3, ushort* __restrict__ pdb) {
  long i = (long)blockIdx.x * 256 + threadIdx.x;
  if (i < 524288) {                 // cpte0 + cpto0
    int o = (int)(i >> 9), s = (int)(i & 511);
    int idx = (o - 2 * s) & 1023;
    cpte0[i] = f2bf(m1w0[idx]);
    cpto0[i] = f2bf(m1w0[1024 + idx]);
  } else if (i < 1572864) {         // cpt1
    long j = i - 524288;
    int o = (int)(j >> 10), kk = (int)(j & 1023);
    cpt1[j] = f2bf(m2w0[(kk & 1) * 1024 + ((o - 2 * (kk >> 1)) & 1023)]);
  } else if (i < 2621440) {         // cpt2
    long j = i - 1572864;
    int o = (int)(j >> 10), kk = (int)(j & 1023);
    cpt2[j] = f2bf(m1w1[(kk & 1) * 1024 + ((o - 2 * (kk >> 1)) & 1023)]);
  } else if (i < 3145728) {         // cpt3
    long j = i - 2621440;
    int o = (int)(j >> 10), kk = (int)(j & 1023);
    cpt3[j] = f2bf(m2w1[(kk & 1) * 512 + ((o - (kk >> 1)) & 511)]);
  } else if (i < 3407872) {         // pdb
    long j = i - 3145728;
    int t = (int)(j >> 9), s = (int)(j & 511);
    pdb[j] = f2bf(fabsf((float)(s - t)) * (1.0f / 511.0f));
  }
}

// ------------------------------------------------------------ MFMA QK^T scores
__global__ __launch_bounds__(256)
void scores_kernel(const ushort* __restrict__ qb, const ushort* __restrict__ kb,
                   ushort* __restrict__ S) {
  int tb = blockIdx.x;              // 8 t-blocks of 64
  int b  = blockIdx.y;              // 64
  int wv = threadIdx.x >> 6, lane = threadIdx.x & 63;
  int fr = lane & 15, fq = lane >> 4;
  int t0 = tb * 64 + wv * 16;
  bf16x8 af = *(const bf16x8*)(qb + ((long)b * 512 + t0 + fr) * 32 + fq * 8);
  const ushort* kbase = kb + (long)b * 512 * 32 + fr * 32 + fq * 8;
  ushort* Sb = S + ((long)b * 512 + t0 + fq * 4) * 512 + fr;
  f32x4 zz = {0.f, 0.f, 0.f, 0.f};
#pragma unroll 4
  for (int st = 0; st < 32; ++st) {
    bf16x8 bfv = *(const bf16x8*)(kbase + st * 512);
    f32x4 acc = __builtin_amdgcn_mfma_f32_16x16x32_bf16(af, bfv, zz, 0, 0, 0);
#pragma unroll
    for (int r = 0; r < 4; ++r)
      Sb[(long)r * 512 + st * 16] = f2bf(acc[r] * 0.17677669529663687f);
  }
}

// =================================================================== 256² GEMM
// Y[b] = A[b] (M x K, row-major) * BT[b] (ncols x K, row-major)^T  [+ Cadd]
// 8-phase schedule (T2 swizzle + T3/T4 counted vmcnt + T5 setprio).
// K is a TEMPLATE param: runtime-K cost 90.7 vs ~62 µs compile-time (round 3).
#define LDS_BUF  65536
#define LDS_BOFF 32768

#define STAGE_A_(buf, h, kt) do { \
  const ushort* gA0_ = Ab + (long)((h)*128 +      sr0) * K + (kt)*64 + slog8; \
  const ushort* gA1_ = Ab + (long)((h)*128 + 64 + sr0) * K + (kt)*64 + slog8; \
  char* dA_ = ldsw + (size_t)(buf) * LDS_BUF + (h)*16384 + tid*16; \
  GLOAD_LDS16(gA0_, dA_); GLOAD_LDS16(gA1_, dA_ + 8192); } while(0)

#define STAGE_B_(buf, h, kt) do { \
  const ushort* gB0_ = Bb + (long)((h)*128 +      sr0) * K + (kt)*64 + slog8; \
  const ushort* gB1_ = Bb + (long)((h)*128 + 64 + sr0) * K + (kt)*64 + slog8; \
  char* dB_ = ldsw + (size_t)(buf) * LDS_BUF + LDS_BOFF + (h)*16384 + tid*16; \
  GLOAD_LDS16(gB0_, dB_); GLOAD_LDS16(gB1_, dB_ + 8192); } while(0)

#define LD_A_(buf, mh) do { \
  const char* aB_ = ldsc + (size_t)(buf) * LDS_BUF; \
  _Pragma("unroll") for (int mi = 0; mi < 4; ++mi) { \
    int ar_ = wm*128 + (mh)*64 + mi*16 + fr; \
    const char* rb_ = aB_ + ar_*128; int sw_ = (ar_&7)<<4; \
    af[mi][0] = *(const bf16x8*)(rb_ + ((fq*16) ^ sw_)); \
    af[mi][1] = *(const bf16x8*)(rb_ + ((64 + fq*16) ^ sw_)); \
  } } while(0)

#define LD_B_(dst, buf, nh) do { \
  const char* bB_ = ldsc + (size_t)(buf) * LDS_BUF + LDS_BOFF; \
  _Pragma("unroll") for (int ni = 0; ni < 2; ++ni) { \
    int br_ = wn*64 + (nh)*32 + ni*16 + fr; \
    const char* rb_ = bB_ + br_*128; int sw_ = (br_&7)<<4; \
    dst[ni][0] = *(const bf16x8*)(rb_ + ((fq*16) ^ sw_)); \
    dst[ni][1] = *(const bf16x8*)(rb_ + ((64 + fq*16) ^ sw_)); \
  } } while(0)

#define QUAD_(mh, nh, bfa) do { \
  __builtin_amdgcn_s_setprio(1); \
  _Pragma("unroll") for (int kk = 0; kk < 2; ++kk) \
  _Pragma("unroll") for (int mi = 0; mi < 4; ++mi) \
  _Pragma("unroll") for (int ni = 0; ni < 2; ++ni) \
    acc[(mh)*4+mi][(nh)*2+ni] = __builtin_amdgcn_mfma_f32_16x16x32_bf16( \
        af[mi][kk], bfa[ni][kk], acc[(mh)*4+mi][(nh)*2+ni], 0, 0, 0); \
  __builtin_amdgcn_s_setprio(0); } while(0)

template<int K, bool FINAL>
__global__ __launch_bounds__(512, 2)
void gemm256_kernel(const ushort* __restrict__ A, long aStride,
                    const ushort* __restrict__ BT, long bStride,
                    void* __restrict__ Out, int ncols, float* __restrict__ stats,
                    const float* __restrict__ Cadd) {
  __shared__ ushort lds[2][2][256 * 64];   // 128 KiB
  const int tid = threadIdx.x;
  const int bm = blockIdx.x, bn = blockIdx.y, b = blockIdx.z;
  constexpr int NKT2 = K >> 7;
  const ushort* Ab = A  + (long)b * aStride + (long)bm * 256 * K;
  const ushort* Bb = BT + (long)b * bStride + (long)bn * 256 * K;
  const int lane = tid & 63;
  const int fr = lane & 15, fq = lane >> 4;
  const int wid = tid >> 6, wm = wid >> 2, wn = wid & 3;
  const int sr0 = tid >> 3;
  const int slog8 = ((tid & 7) ^ (sr0 & 7)) * 8;
  const char* ldsc = (const char*)&lds[0][0][0];
  char*       ldsw = (char*)&lds[0][0][0];

  f32x4 acc[8][4] = {};
  bf16x8 af[4][2], bf0[2][2], bf1[2][2];

  STAGE_B_(0, 0, 0); STAGE_B_(0, 1, 0);
  STAGE_A_(0, 0, 0); STAGE_A_(0, 1, 0);
  STAGE_B_(1, 0, 1); STAGE_B_(1, 1, 1);
  WAITV4();
  BAR();

  for (int i = 0; i < NKT2; ++i) {
    const int t1 = 2 * i + 1, t2 = 2 * i + 2, t3 = 2 * i + 3;
    const bool st = (i < NKT2 - 1);
    LD_A_(0, 0); LD_B_(bf0, 0, 0);
    STAGE_A_(1, 0, t1);
    BAR(); WAITL(); QUAD_(0, 0, bf0); BAR();

    LD_B_(bf1, 0, 1);
    STAGE_A_(1, 1, t1);
    BAR(); WAITL(); QUAD_(0, 1, bf1); BAR();

    LD_A_(0, 1);
    if (st) STAGE_B_(0, 0, t2);
    BAR(); WAITL(); QUAD_(1, 1, bf1); BAR();

    if (st) { STAGE_B_(0, 1, t2); WAITV4(); } else { WAITV0(); }
    BAR(); QUAD_(1, 0, bf0); BAR();

    LD_A_(1, 0); LD_B_(bf0, 1, 0);
    if (st) STAGE_A_(0, 0, t2);
    BAR(); WAITL(); QUAD_(0, 0, bf0); BAR();

    LD_B_(bf1, 1, 1);
    if (st) STAGE_A_(0, 1, t2);
    BAR(); WAITL(); QUAD_(0, 1, bf1); BAR();

    LD_A_(1, 1);
    if (st) STAGE_B_(1, 0, t3);
    BAR(); WAITL(); QUAD_(1, 1, bf1); BAR();

    if (st) { STAGE_B_(1, 1, t3); WAITV4(); }
    BAR(); QUAD_(1, 0, bf0); BAR();
  }

  const int r0 = bm * 256 + wm * 128;
  const int c0 = bn * 256 + wn * 64;
  if (!FINAL) {
    ushort* Yb = (ushort*)Out + (long)b * 512 * ncols;
    float s1 = 0.f, s2 = 0.f;
#pragma unroll
    for (int mi = 0; mi < 8; ++mi)
#pragma unroll
      for (int ni = 0; ni < 4; ++ni)
#pragma unroll
        for (int r = 0; r < 4; ++r) {
          float v = acc[mi][ni][r];
          int row = r0 + mi * 16 + fq * 4 + r;
          int col = c0 + ni * 16 + fr;
          if (Cadd) v += Cadd[(long)row * ncols + col];
          s1 += v; s2 += v * v;
          Yb[(long)row * ncols + col] = f2bf(v);
        }
    __syncthreads();
    float* red = (float*)&lds[0][0][0];
    red[tid] = s1; red[tid + 512] = s2;
    __syncthreads();
    for (int off = 256; off > 0; off >>= 1) {
      if (tid < off) { red[tid] += red[tid + off]; red[512 + tid] += red[512 + tid + off]; }
      __syncthreads();
    }
    if (tid == 0) {
      atomicAdd(&stats[b * 2],     red[0]);
      atomicAdd(&stats[b * 2 + 1], red[512]);
    }
  } else {
    float* Lb = (float*)Out + (long)b * 512 * ncols;
#pragma unroll
    for (int mi = 0; mi < 8; ++mi)
#pragma unroll
      for (int ni = 0; ni < 4; ++ni)
#pragma unroll
        for (int r = 0; r < 4; ++r) {
          int row = r0 + mi * 16 + fq * 4 + r;
          int col = c0 + ni * 16 + fr;
          Lb[(long)row * ncols + col] = acc[mi][ni][r];
        }
  }
}

// --------------------------------------------- LN + gelu + pair-transpose fused
__global__ __launch_bounds__(256)
void apply_kernel(const ushort* __restrict__ Y, const float* __restrict__ stats,
                  const float* __restrict__ g, const float* __restrict__ bia,
                  ushort* __restrict__ P) {
  __shared__ ushort2 tile[32][33];
  int ti = blockIdx.x;
  int si = blockIdx.y;
  int b  = blockIdx.z;
  float mu  = stats[b * 2] * (1.0f / MTOT);
  float var = stats[b * 2 + 1] * (1.0f / MTOT) - mu * mu;
  float rstd = rsqrtf(var + 1e-5f);
  int tx = threadIdx.x & 31, ty = threadIdx.x >> 5;
  const ushort* Yb = Y + (long)b * 512 * 1024;
#pragma unroll
  for (int i = 0; i < 4; ++i) {
    int t  = ti * 32 + ty + i * 8;
    int sp = si * 32 + tx;
    ushort2 yv = *(const ushort2*)(Yb + (long)t * 1024 + 2 * sp);
    float2 gv = *(const float2*)(g   + (long)t * 1024 + 2 * sp);
    float2 bv = *(const float2*)(bia + (long)t * 1024 + 2 * sp);
    float y0 = (bf2f(yv.x) - mu) * rstd * gv.x + bv.x;
    float y1 = (bf2f(yv.y) - mu) * rstd * gv.y + bv.y;
    ushort2 o; o.x = f2bf(gelu_exact(y0)); o.y = f2bf(gelu_exact(y1));
    tile[ty + i * 8][tx] = o;
  }
  __syncthreads();
  ushort* Pb = P + (long)b * 512 * 1024;
#pragma unroll
  for (int i = 0; i < 4; ++i) {
    int srow = si * 32 + ty + i * 8;
    int tcol = ti * 32 + tx;
    ushort2 v = tile[tx][ty + i * 8];
    *(ushort2*)(Pb + (long)srow * 1024 + 2 * tcol) = v;
  }
}

// ----------------------------------------------------- fused softmax + attn@V
__global__ __launch_bounds__(256)
void smax_av_kernel(const float* __restrict__ L, const float* __restrict__ vp,
                    float* __restrict__ out) {
  __shared__ float Lt[32][513];
  int bh = blockIdx.x;   // 64
  int at = blockIdx.y;   // 16 tiles of 32 rows
  int n = bh >> 3, h = bh & 7;
  int wv = threadIdx.x >> 6, lane = threadIdx.x & 63;
  for (int rr = 0; rr < 8; ++rr) {
    int row = wv * 8 + rr;
    int a = at * 32 + row;
    const float* Lr = L + ((long)bh * 512 + a) * 512;
    float e[8];
#pragma unroll
    for (int j = 0; j < 8; ++j) e[j] = Lr[j * 64 + lane];
    float m = e[0];
#pragma unroll
    for (int j = 1; j < 8; ++j) m = fmaxf(m, e[j]);
    for (int off = 32; off > 0; off >>= 1) m = fmaxf(m, __shfl_xor(m, off, 64));
    float s = 0.f;
#pragma unroll
    for (int j = 0; j < 8; ++j) { e[j] = expf(e[j] - m); s += e[j]; }
    for (int off = 32; off > 0; off >>= 1) s += __shfl_xor(s, off, 64);
    float inv = 1.0f / s;
#pragma unroll
    for (int j = 0; j < 8; ++j) Lt[row][j * 64 + lane] = e[j] * inv;
  }
  __syncthreads();
  int r  = threadIdx.x & 31;
  int d0 = (threadIdx.x >> 5) * 4;
  const float* vb = vp + ((long)n * 256 + h * 32) * 512;
  float a0 = 0.f, a1 = 0.f, a2 = 0.f, a3 = 0.f;
  for (int bc = 0; bc < 512; bc += 4) {
    float4 v0 = *(const float4*)(vb + (d0 + 0) * 512 + bc);
    float4 v1 = *(const float4*)(vb + (d0 + 1) * 512 + bc);
    float4 v2 = *(const float4*)(vb + (d0 + 2) * 512 + bc);
    float4 v3 = *(const float4*)(vb + (d0 + 3) * 512 + bc);
    float p0 = Lt[r][bc], p1 = Lt[r][bc + 1], p2 = Lt[r][bc + 2], p3 = Lt[r][bc + 3];
    a0 = fmaf(p0, v0.x, fmaf(p1, v0.y, fmaf(p2, v0.z, fmaf(p3, v0.w, a0))));
    a1 = fmaf(p0, v1.x, fmaf(p1, v1.y, fmaf(p2, v1.z, fmaf(p3, v1.w, a1))));
    a2 = fmaf(p0, v2.x, fmaf(p1, v2.y, fmaf(p2, v2.z, fmaf(p3, v2.w, a2))));
    a3 = fmaf(p0, v3.x, fmaf(p1, v3.y, fmaf(p2, v3.z, fmaf(p3, v3.w, a3))));
  }
  int a = at * 32 + r;
  float* ob = out + ((long)n * 256 + h * 32) * 512;
  ob[(d0 + 0) * 512 + a] = a0;
  ob[(d0 + 1) * 512 + a] = a1;
  ob[(d0 + 2) * 512 + a] = a2;
  ob[(d0 + 3) * 512 + a] = a3;
}

// -------------------------------------------------------------------- launch
extern "C" void kernel_launch(void* const* d_in, const int* in_sizes, int n_in,
                              void* d_out, int out_size, void* d_ws, size_t ws_size,
                              hipStream_t stream) {
  const float* x     = (const float*)d_in[0];
  const float* Wq    = (const float*)d_in[1];
  const float* Wk    = (const float*)d_in[2];
  const float* Wv    = (const float*)d_in[3];
  const float* m1w0  = (const float*)d_in[4];
  const float* m2w0  = (const float*)d_in[5];
  const float* m1w1  = (const float*)d_in[6];
  const float* m2w1  = (const float*)d_in[7];
  const float* ln1g0 = (const float*)d_in[8];
  const float* ln1b0 = (const float*)d_in[9];
  const float* ln2g0 = (const float*)d_in[10];
  const float* ln2b0 = (const float*)d_in[11];
  const float* ln1g1 = (const float*)d_in[12];
  const float* ln1b1 = (const float*)d_in[13];

  char* w = (char*)d_ws;
  float*  vp     = (float*) (w + 0);                 // 4 MB
  ushort* qb     = (ushort*)(w + (4ull  << 20));     // 2 MB
  ushort* kb     = (ushort*)(w + (6ull  << 20));     // 2 MB
  float*  stats  = (float*) (w + (8ull  << 20));     // small
  ushort* cpte0  = (ushort*)(w + (9ull  << 20));     // 1 MB
  ushort* cpto0  = (ushort*)(w + (10ull << 20));     // 1 MB
  ushort* cpt1   = (ushort*)(w + (11ull << 20));     // 2 MB
  ushort* cpt2   = (ushort*)(w + (13ull << 20));     // 2 MB
  ushort* cpt3   = (ushort*)(w + (15ull << 20));     // 1 MB
  ushort* pdb    = (ushort*)(w + (16ull << 20));     // 0.5 MB
  float*  pdpart = (float*) (w + (17ull << 20));     // 2 MB
  ushort* bufA   = (ushort*)(w + (20ull << 20));     // 64 MB (S in first 32 MB)
  ushort* bufB   = (ushort*)(w + (84ull << 20));     // 64 MB (also L as f32)
  ushort* S      = bufA;
  float*  L      = (float*)bufB;
  float*  outp   = (float*)d_out;

  hipMemsetAsync(stats, 0, 3 * NB * 2 * sizeof(float), stream);

  proj_kernel<<<dim3(2, 256, 8), 256, 0, stream>>>(x, Wq, Wk, Wv, qb, kb, vp);
  prep_kernel<<<13312, 256, 0, stream>>>(m1w0, m2w0, m1w1, m2w1,
                                         cpte0, cpto0, cpt1, cpt2, cpt3, pdb);
  scores_kernel<<<dim3(8, 64), 256, 0, stream>>>(qb, kb, S);
  // pd_part[t][o] = sum_s pdb[t,s] * cpto0[o,s]   (batch-independent)
  gemm256_kernel<512, true><<<dim3(2, 4, 1), 512, 0, stream>>>(
      pdb, 0, cpto0, 0, pdpart, 1024, nullptr, nullptr);
  // Y1 = S @ cpte0^T + pd_part
  gemm256_kernel<512, false><<<dim3(2, 4, 64), 512, 0, stream>>>(
      S, 512L * 512, cpte0, 0, bufB, 1024, stats, pdpart);
  apply_kernel<<<dim3(16, 16, 64), 256, 0, stream>>>(bufB, stats, ln1g0, ln1b0, bufA);
  gemm256_kernel<1024, false><<<dim3(2, 4, 64), 512, 0, stream>>>(
      bufA, 512L * 1024, cpt1, 0, bufB, 1024, stats + 128, nullptr);
  apply_kernel<<<dim3(16, 16, 64), 256, 0, stream>>>(bufB, stats + 128, ln2g0, ln2b0, bufA);
  gemm256_kernel<1024, false><<<dim3(2, 4, 64), 512, 0, stream>>>(
      bufA, 512L * 1024, cpt2, 0, bufB, 1024, stats + 256, nullptr);
  apply_kernel<<<dim3(16, 16, 64), 256, 0, stream>>>(bufB, stats + 256, ln1g1, ln1b1, bufA);
  // L[b, a, t] = sum_k cpt3[a,k] * P3'[t,k]   (softmax-ready layout)
  gemm256_kernel<1024, true><<<dim3(2, 2, 64), 512, 0, stream>>>(
      cpt3, 0, bufA, 512L * 1024, L, 512, nullptr, nullptr);
  smax_av_kernel<<<dim3(64, 16), 256, 0, stream>>>(L, vp, outp);
}

// Round 6
// 513.566 us; speedup vs baseline: 1.2695x; 1.0053x over previous
//
#include <hip/hip_runtime.h>
#include <hip/hip_bf16.h>
#include <math.h>

// Problem constants
#define CDIM 256
#define TDIM 512
#define T2   1024
#define NB   64      // N*H batches
#define MTOT 524288.0f   // T*2T elements per batch for LN

typedef __bf16 bf16x8 __attribute__((ext_vector_type(8)));
typedef float  f32x4  __attribute__((ext_vector_type(4)));
typedef ushort ushort8v __attribute__((ext_vector_type(8)));
typedef ushort ushort4v __attribute__((ext_vector_type(4)));

__device__ __forceinline__ ushort f2bf(float f) {
  union { float f; unsigned u; } v; v.f = f;
  unsigned r = v.u + 0x7fffu + ((v.u >> 16) & 1u);
  return (ushort)(r >> 16);
}
__device__ __forceinline__ float bf2f(ushort h) {
  union { unsigned u; float f; } v; v.u = ((unsigned)h) << 16;
  return v.f;
}
__device__ __forceinline__ float gelu_exact(float x) {
  return 0.5f * x * (1.0f + erff(x * 0.7071067811865475f));
}

#define TO_LDS(p)  ((__attribute__((address_space(3))) void*)(unsigned)(uintptr_t)(p))
#define TO_GLB(p)  ((const __attribute__((address_space(1))) void*)(uintptr_t)(p))
#define GLOAD_LDS16(g, l) __builtin_amdgcn_global_load_lds(TO_GLB(g), TO_LDS(l), 16, 0, 0)

#define BAR()    asm volatile("s_barrier" ::: "memory")
#define WAITL()  asm volatile("s_waitcnt lgkmcnt(0)" ::: "memory")
#define WAITV4() asm volatile("s_waitcnt vmcnt(4)" ::: "memory")
#define WAITV0() asm volatile("s_waitcnt vmcnt(0)" ::: "memory")

// ---------------------------------------------------------------- projections
// qb/kb: bf16 [b=n*8+h][t][d(32)]  (MFMA-ready, 64B rows); vp: f32 [n][o][t]
__global__ __launch_bounds__(256)
void proj_kernel(const float* __restrict__ x, const float* __restrict__ Wq,
                 const float* __restrict__ Wk, const float* __restrict__ Wv,
                 ushort* __restrict__ qb, ushort* __restrict__ kb,
                 float* __restrict__ vp) {
  int t = blockIdx.x * 256 + threadIdx.x;
  int o = blockIdx.y;
  int n = blockIdx.z;
  const float* xn = x + (long)n * CDIM * TDIM;
  float aq = 0.f, ak = 0.f, av = 0.f;
  for (int c = 0; c < CDIM; ++c) {
    float xv = xn[c * TDIM + t];
    aq = fmaf(Wq[o * CDIM + c], xv, aq);
    ak = fmaf(Wk[o * CDIM + c], xv, ak);
    av = fmaf(Wv[o * CDIM + c], xv, av);
  }
  int h = o >> 5, d = o & 31;
  long bidx = (((long)(n * 8 + h) * 512) + t) * 32 + d;
  qb[bidx] = f2bf(aq);
  kb[bidx] = f2bf(ak);
  vp[((long)n * 256 + o) * TDIM + t] = av;
}

// ---------------------------------------- all small precompute in one kernel
__global__ __launch_bounds__(256)
void prep_kernel(const float* __restrict__ m1w0, const float* __restrict__ m2w0,
                 const float* __restrict__ m1w1, const float* __restrict__ m2w1,
                 ushort* __restrict__ cpte0, ushort* __restrict__ cpto0,
                 ushort* __restrict__ cpt1, ushort* __restrict__ cpt2,
                 ushort* __restrict__ cpt3, ushort* __restrict__ pdb) {
  long i = (long)blockIdx.x * 256 + threadIdx.x;
  if (i < 524288) {                 // cpte0 + cpto0
    int o = (int)(i >> 9), s = (int)(i & 511);
    int idx = (o - 2 * s) & 1023;
    cpte0[i] = f2bf(m1w0[idx]);
    cpto0[i] = f2bf(m1w0[1024 + idx]);
  } else if (i < 1572864) {         // cpt1
    long j = i - 524288;
    int o = (int)(j >> 10), kk = (int)(j & 1023);
    cpt1[j] = f2bf(m2w0[(kk & 1) * 1024 + ((o - 2 * (kk >> 1)) & 1023)]);
  } else if (i < 2621440) {         // cpt2
    long j = i - 1572864;
    int o = (int)(j >> 10), kk = (int)(j & 1023);
    cpt2[j] = f2bf(m1w1[(kk & 1) * 1024 + ((o - 2 * (kk >> 1)) & 1023)]);
  } else if (i < 3145728) {         // cpt3
    long j = i - 2621440;
    int o = (int)(j >> 10), kk = (int)(j & 1023);
    cpt3[j] = f2bf(m2w1[(kk & 1) * 512 + ((o - (kk >> 1)) & 511)]);
  } else if (i < 3407872) {         // pdb
    long j = i - 3145728;
    int t = (int)(j >> 9), s = (int)(j & 511);
    pdb[j] = f2bf(fabsf((float)(s - t)) * (1.0f / 511.0f));
  }
}

// -------------------- pack LN params to bf16: gbb[t][sp] = {g0,b0,g1,b1} (8 B)
// Runs AFTER gemm1 (aliases dead qb/kb/cpte0 workspace). 2 MB per layer ->
// fits per-XCD L2 (vs 8 MB f32 = 512 MB L3 re-reads per apply).
__global__ __launch_bounds__(256)
void prep2_kernel(const float* __restrict__ g0, const float* __restrict__ b0,
                  const float* __restrict__ g1, const float* __restrict__ b1,
                  const float* __restrict__ g2, const float* __restrict__ b2,
                  ushort* __restrict__ gbb0, ushort* __restrict__ gbb1,
                  ushort* __restrict__ gbb2) {
  long i = (long)blockIdx.x * 256 + threadIdx.x;   // 3 * 262144
  int set = (int)(i >> 18);
  long j = i & 262143;
  const float* g = set == 0 ? g0 : (set == 1 ? g1 : g2);
  const float* b = set == 0 ? b0 : (set == 1 ? b1 : b2);
  ushort* gbb    = set == 0 ? gbb0 : (set == 1 ? gbb1 : gbb2);
  float2 gv = *(const float2*)(g + 2 * j);
  float2 bv = *(const float2*)(b + 2 * j);
  ushort4v o; o[0] = f2bf(gv.x); o[1] = f2bf(bv.x); o[2] = f2bf(gv.y); o[3] = f2bf(bv.y);
  *(ushort4v*)(gbb + 4 * j) = o;
}

// ------------------------------------------------------------ MFMA QK^T scores
__global__ __launch_bounds__(256)
void scores_kernel(const ushort* __restrict__ qb, const ushort* __restrict__ kb,
                   ushort* __restrict__ S) {
  int tb = blockIdx.x;              // 8 t-blocks of 64
  int b  = blockIdx.y;              // 64
  int wv = threadIdx.x >> 6, lane = threadIdx.x & 63;
  int fr = lane & 15, fq = lane >> 4;
  int t0 = tb * 64 + wv * 16;
  bf16x8 af = *(const bf16x8*)(qb + ((long)b * 512 + t0 + fr) * 32 + fq * 8);
  const ushort* kbase = kb + (long)b * 512 * 32 + fr * 32 + fq * 8;
  ushort* Sb = S + ((long)b * 512 + t0 + fq * 4) * 512 + fr;
  f32x4 zz = {0.f, 0.f, 0.f, 0.f};
#pragma unroll 4
  for (int st = 0; st < 32; ++st) {
    bf16x8 bfv = *(const bf16x8*)(kbase + st * 512);
    f32x4 acc = __builtin_amdgcn_mfma_f32_16x16x32_bf16(af, bfv, zz, 0, 0, 0);
#pragma unroll
    for (int r = 0; r < 4; ++r)
      Sb[(long)r * 512 + st * 16] = f2bf(acc[r] * 0.17677669529663687f);
  }
}

// =================================================================== 256² GEMM
// Y[b] = A[b] (M x K, row-major) * BT[b] (ncols x K, row-major)^T  [+ Cadd]
// 4-compartment schedule (merged from 8-phase: same staging order, same counted
// vmcnt discipline, half the barriers — round 5 showed ~50% of loop time was
// barrier/drain overhead at 16 barriers/iter).
#define LDS_BUF  65536
#define LDS_BOFF 32768

#define STAGE_A_(buf, h, kt) do { \
  const ushort* gA0_ = Ab + (long)((h)*128 +      sr0) * K + (kt)*64 + slog8; \
  const ushort* gA1_ = Ab + (long)((h)*128 + 64 + sr0) * K + (kt)*64 + slog8; \
  char* dA_ = ldsw + (size_t)(buf) * LDS_BUF + (h)*16384 + tid*16; \
  GLOAD_LDS16(gA0_, dA_); GLOAD_LDS16(gA1_, dA_ + 8192); } while(0)

#define STAGE_B_(buf, h, kt) do { \
  const ushort* gB0_ = Bb + (long)((h)*128 +      sr0) * K + (kt)*64 + slog8; \
  const ushort* gB1_ = Bb + (long)((h)*128 + 64 + sr0) * K + (kt)*64 + slog8; \
  char* dB_ = ldsw + (size_t)(buf) * LDS_BUF + LDS_BOFF + (h)*16384 + tid*16; \
  GLOAD_LDS16(gB0_, dB_); GLOAD_LDS16(gB1_, dB_ + 8192); } while(0)

#define LD_A_(buf, mh) do { \
  const char* aB_ = ldsc + (size_t)(buf) * LDS_BUF; \
  _Pragma("unroll") for (int mi = 0; mi < 4; ++mi) { \
    int ar_ = wm*128 + (mh)*64 + mi*16 + fr; \
    const char* rb_ = aB_ + ar_*128; int sw_ = (ar_&7)<<4; \
    af[mi][0] = *(const bf16x8*)(rb_ + ((fq*16) ^ sw_)); \
    af[mi][1] = *(const bf16x8*)(rb_ + ((64 + fq*16) ^ sw_)); \
  } } while(0)

#define LD_B_(dst, buf, nh) do { \
  const char* bB_ = ldsc + (size_t)(buf) * LDS_BUF + LDS_BOFF; \
  _Pragma("unroll") for (int ni = 0; ni < 2; ++ni) { \
    int br_ = wn*64 + (nh)*32 + ni*16 + fr; \
    const char* rb_ = bB_ + br_*128; int sw_ = (br_&7)<<4; \
    dst[ni][0] = *(const bf16x8*)(rb_ + ((fq*16) ^ sw_)); \
    dst[ni][1] = *(const bf16x8*)(rb_ + ((64 + fq*16) ^ sw_)); \
  } } while(0)

#define QUAD_(mh, nh, bfa) do { \
  __builtin_amdgcn_s_setprio(1); \
  _Pragma("unroll") for (int kk = 0; kk < 2; ++kk) \
  _Pragma("unroll") for (int mi = 0; mi < 4; ++mi) \
  _Pragma("unroll") for (int ni = 0; ni < 2; ++ni) \
    acc[(mh)*4+mi][(nh)*2+ni] = __builtin_amdgcn_mfma_f32_16x16x32_bf16( \
        af[mi][kk], bfa[ni][kk], acc[(mh)*4+mi][(nh)*2+ni], 0, 0, 0); \
  __builtin_amdgcn_s_setprio(0); } while(0)

template<int K, bool FINAL>
__global__ __launch_bounds__(512, 2)
void gemm256_kernel(const ushort* __restrict__ A, long aStride,
                    const ushort* __restrict__ BT, long bStride,
                    void* __restrict__ Out, int ncols, float* __restrict__ stats,
                    const float* __restrict__ Cadd) {
  __shared__ ushort lds[2][2][256 * 64];   // 128 KiB
  const int tid = threadIdx.x;
  const int bm = blockIdx.x, bn = blockIdx.y, b = blockIdx.z;
  constexpr int NKT2 = K >> 7;
  const ushort* Ab = A  + (long)b * aStride + (long)bm * 256 * K;
  const ushort* Bb = BT + (long)b * bStride + (long)bn * 256 * K;
  const int lane = tid & 63;
  const int fr = lane & 15, fq = lane >> 4;
  const int wid = tid >> 6, wm = wid >> 2, wn = wid & 3;
  const int sr0 = tid >> 3;
  const int slog8 = ((tid & 7) ^ (sr0 & 7)) * 8;
  const char* ldsc = (const char*)&lds[0][0][0];
  char*       ldsw = (char*)&lds[0][0][0];

  f32x4 acc[8][4] = {};
  bf16x8 af[4][2], bf0[2][2], bf1[2][2];

  STAGE_B_(0, 0, 0); STAGE_B_(0, 1, 0);
  STAGE_A_(0, 0, 0); STAGE_A_(0, 1, 0);
  STAGE_B_(1, 0, 1); STAGE_B_(1, 1, 1);
  WAITV4();
  BAR();

  for (int i = 0; i < NKT2; ++i) {
    const int t1 = 2 * i + 1, t2 = 2 * i + 2, t3 = 2 * i + 3;
    const bool st = (i < NKT2 - 1);
    // C1: tile 2i quadrants (0,0)+(0,1); prefetch next-tile A
    LD_A_(0, 0); LD_B_(bf0, 0, 0); LD_B_(bf1, 0, 1);
    STAGE_A_(1, 0, t1); STAGE_A_(1, 1, t1);
    BAR(); WAITL();
    QUAD_(0, 0, bf0); QUAD_(0, 1, bf1);
    BAR();
    // C2: quadrants (1,1)+(1,0); prefetch tile-2i+2 B
    LD_A_(0, 1);
    if (st) { STAGE_B_(0, 0, t2); STAGE_B_(0, 1, t2); WAITV4(); } else { WAITV0(); }
    BAR(); WAITL();
    QUAD_(1, 1, bf1); QUAD_(1, 0, bf0);
    BAR();
    // C3: tile 2i+1 quadrants (0,0)+(0,1); prefetch tile-2i+2 A
    LD_A_(1, 0); LD_B_(bf0, 1, 0); LD_B_(bf1, 1, 1);
    if (st) { STAGE_A_(0, 0, t2); STAGE_A_(0, 1, t2); }
    BAR(); WAITL();
    QUAD_(0, 0, bf0); QUAD_(0, 1, bf1);
    BAR();
    // C4: quadrants (1,1)+(1,0); prefetch tile-2i+3 B
    LD_A_(1, 1);
    if (st) { STAGE_B_(1, 0, t3); STAGE_B_(1, 1, t3); WAITV4(); }
    BAR(); WAITL();
    QUAD_(1, 1, bf1); QUAD_(1, 0, bf0);
    BAR();
  }

  const int r0 = bm * 256 + wm * 128;
  const int c0 = bn * 256 + wn * 64;
  if (!FINAL) {
    ushort* Yb = (ushort*)Out + (long)b * 512 * ncols;
    float s1 = 0.f, s2 = 0.f;
#pragma unroll
    for (int mi = 0; mi < 8; ++mi)
#pragma unroll
      for (int ni = 0; ni < 4; ++ni)
#pragma unroll
        for (int r = 0; r < 4; ++r) {
          float v = acc[mi][ni][r];
          int row = r0 + mi * 16 + fq * 4 + r;
          int col = c0 + ni * 16 + fr;
          if (Cadd) v += Cadd[(long)row * ncols + col];
          s1 += v; s2 += v * v;
          Yb[(long)row * ncols + col] = f2bf(v);
        }
    __syncthreads();
    float* red = (float*)&lds[0][0][0];
    red[tid] = s1; red[tid + 512] = s2;
    __syncthreads();
    for (int off = 256; off > 0; off >>= 1) {
      if (tid < off) { red[tid] += red[tid + off]; red[512 + tid] += red[512 + tid + off]; }
      __syncthreads();
    }
    if (tid == 0) {
      atomicAdd(&stats[b * 2],     red[0]);
      atomicAdd(&stats[b * 2 + 1], red[512]);
    }
  } else {
    float* Lb = (float*)Out + (long)b * 512 * ncols;
#pragma unroll
    for (int mi = 0; mi < 8; ++mi)
#pragma unroll
      for (int ni = 0; ni < 4; ++ni)
#pragma unroll
        for (int r = 0; r < 4; ++r) {
          int row = r0 + mi * 16 + fq * 4 + r;
          int col = c0 + ni * 16 + fr;
          Lb[(long)row * ncols + col] = acc[mi][ni][r];
        }
  }
}

// --------------------------------------------- LN + gelu + pair-transpose fused
// P'[b, s, 2t+r] = gelu( (Y[b,t,2s+r]-mu)*rstd*g + bias )
// 16-B vector loads/stores; bf16 gbb param table (2 MB, L2-resident).
__global__ __launch_bounds__(256)
void apply_kernel(const ushort* __restrict__ Y, const float* __restrict__ stats,
                  const ushort* __restrict__ gbb, ushort* __restrict__ P) {
  __shared__ ushort2 tile[32][65];
  int ti = blockIdx.x;   // 16 t-tiles of 32
  int si = blockIdx.y;   // 8 s-tiles of 64 pairs
  int b  = blockIdx.z;   // 64
  float mu  = stats[b * 2] * (1.0f / MTOT);
  float var = stats[b * 2 + 1] * (1.0f / MTOT) - mu * mu;
  float rstd = rsqrtf(var + 1e-5f);
  const ushort* Yb = Y + (long)b * 512 * 1024;
  int tr  = threadIdx.x >> 4;          // 0..15
  int sp4 = (threadIdx.x & 15) * 4;    // pair offset 0..60
#pragma unroll
  for (int pass = 0; pass < 2; ++pass) {
    int t  = ti * 32 + pass * 16 + tr;
    int sp = si * 64 + sp4;
    ushort8v yv  = *(const ushort8v*)(Yb + (long)t * 1024 + 2 * sp);
    ushort8v gbA = *(const ushort8v*)(gbb + ((long)t * 512 + sp) * 4);
    ushort8v gbB = *(const ushort8v*)(gbb + ((long)t * 512 + sp + 2) * 4);
#pragma unroll
    for (int j = 0; j < 4; ++j) {
      int base = (j & 1) * 4;
      ushort gg0 = (j < 2) ? gbA[base + 0] : gbB[base + 0];
      ushort bb0 = (j < 2) ? gbA[base + 1] : gbB[base + 1];
      ushort gg1 = (j < 2) ? gbA[base + 2] : gbB[base + 2];
      ushort bb1 = (j < 2) ? gbA[base + 3] : gbB[base + 3];
      float y0 = (bf2f(yv[2 * j])     - mu) * rstd * bf2f(gg0) + bf2f(bb0);
      float y1 = (bf2f(yv[2 * j + 1]) - mu) * rstd * bf2f(gg1) + bf2f(bb1);
      ushort2 o; o.x = f2bf(gelu_exact(y0)); o.y = f2bf(gelu_exact(y1));
      tile[pass * 16 + tr][sp4 + j] = o;
    }
  }
  __syncthreads();
  ushort* Pb = P + (long)b * 512 * 1024;
  int srow = threadIdx.x >> 3;         // 0..31
  int t4   = (threadIdx.x & 7) * 4;    // 0..28
#pragma unroll
  for (int pass = 0; pass < 2; ++pass) {
    int scol = pass * 32 + srow;
    int s = si * 64 + scol;
    ushort2 v0 = tile[t4 + 0][scol];
    ushort2 v1 = tile[t4 + 1][scol];
    ushort2 v2 = tile[t4 + 2][scol];
    ushort2 v3 = tile[t4 + 3][scol];
    int tcol0 = ti * 32 + t4;
    ushort8v w2 = {v0.x, v0.y, v1.x, v1.y, v2.x, v2.y, v3.x, v3.y};
    *(ushort8v*)(Pb + (long)s * 1024 + 2 * tcol0) = w2;
  }
}

// ----------------------------------------------------- fused softmax + attn@V
__global__ __launch_bounds__(256)
void smax_av_kernel(const float* __restrict__ L, const float* __restrict__ vp,
                    float* __restrict__ out) {
  __shared__ float Lt[32][513];
  int bh = blockIdx.x;   // 64
  int at = blockIdx.y;   // 16 tiles of 32 rows
  int n = bh >> 3, h = bh & 7;
  int wv = threadIdx.x >> 6, lane = threadIdx.x & 63;
  for (int rr = 0; rr < 8; ++rr) {
    int row = wv * 8 + rr;
    int a = at * 32 + row;
    const float* Lr = L + ((long)bh * 512 + a) * 512;
    float e[8];
#pragma unroll
    for (int j = 0; j < 8; ++j) e[j] = Lr[j * 64 + lane];
    float m = e[0];
#pragma unroll
    for (int j = 1; j < 8; ++j) m = fmaxf(m, e[j]);
    for (int off = 32; off > 0; off >>= 1) m = fmaxf(m, __shfl_xor(m, off, 64));
    float s = 0.f;
#pragma unroll
    for (int j = 0; j < 8; ++j) { e[j] = expf(e[j] - m); s += e[j]; }
    for (int off = 32; off > 0; off >>= 1) s += __shfl_xor(s, off, 64);
    float inv = 1.0f / s;
#pragma unroll
    for (int j = 0; j < 8; ++j) Lt[row][j * 64 + lane] = e[j] * inv;
  }
  __syncthreads();
  int r  = threadIdx.x & 31;
  int d0 = (threadIdx.x >> 5) * 4;
  const float* vb = vp + ((long)n * 256 + h * 32) * 512;
  float a0 = 0.f, a1 = 0.f, a2 = 0.f, a3 = 0.f;
  for (int bc = 0; bc < 512; bc += 4) {
    float4 v0 = *(const float4*)(vb + (d0 + 0) * 512 + bc);
    float4 v1 = *(const float4*)(vb + (d0 + 1) * 512 + bc);
    float4 v2 = *(const float4*)(vb + (d0 + 2) * 512 + bc);
    float4 v3 = *(const float4*)(vb + (d0 + 3) * 512 + bc);
    float p0 = Lt[r][bc], p1 = Lt[r][bc + 1], p2 = Lt[r][bc + 2], p3 = Lt[r][bc + 3];
    a0 = fmaf(p0, v0.x, fmaf(p1, v0.y, fmaf(p2, v0.z, fmaf(p3, v0.w, a0))));
    a1 = fmaf(p0, v1.x, fmaf(p1, v1.y, fmaf(p2, v1.z, fmaf(p3, v1.w, a1))));
    a2 = fmaf(p0, v2.x, fmaf(p1, v2.y, fmaf(p2, v2.z, fmaf(p3, v2.w, a2))));
    a3 = fmaf(p0, v3.x, fmaf(p1, v3.y, fmaf(p2, v3.z, fmaf(p3, v3.w, a3))));
  }
  int a = at * 32 + r;
  float* ob = out + ((long)n * 256 + h * 32) * 512;
  ob[(d0 + 0) * 512 + a] = a0;
  ob[(d0 + 1) * 512 + a] = a1;
  ob[(d0 + 2) * 512 + a] = a2;
  ob[(d0 + 3) * 512 + a] = a3;
}

// -------------------------------------------------------------------- launch
extern "C" void kernel_launch(void* const* d_in, const int* in_sizes, int n_in,
                              void* d_out, int out_size, void* d_ws, size_t ws_size,
                              hipStream_t stream) {
  const float* x     = (const float*)d_in[0];
  const float* Wq    = (const float*)d_in[1];
  const float* Wk    = (const float*)d_in[2];
  const float* Wv    = (const float*)d_in[3];
  const float* m1w0  = (const float*)d_in[4];
  const float* m2w0  = (const float*)d_in[5];
  const float* m1w1  = (const float*)d_in[6];
  const float* m2w1  = (const float*)d_in[7];
  const float* ln1g0 = (const float*)d_in[8];
  const float* ln1b0 = (const float*)d_in[9];
  const float* ln2g0 = (const float*)d_in[10];
  const float* ln2b0 = (const float*)d_in[11];
  const float* ln1g1 = (const float*)d_in[12];
  const float* ln1b1 = (const float*)d_in[13];

  char* w = (char*)d_ws;
  float*  vp     = (float*) (w + 0);                 // 4 MB
  ushort* qb     = (ushort*)(w + (4ull  << 20));     // 2 MB (later: gbb0)
  ushort* kb     = (ushort*)(w + (6ull  << 20));     // 2 MB (later: gbb1)
  float*  stats  = (float*) (w + (8ull  << 20));     // small
  ushort* cpte0  = (ushort*)(w + (9ull  << 20));     // 1 MB (later: gbb2 lo)
  ushort* cpto0  = (ushort*)(w + (10ull << 20));     // 1 MB (later: gbb2 hi)
  ushort* cpt1   = (ushort*)(w + (11ull << 20));     // 2 MB
  ushort* cpt2   = (ushort*)(w + (13ull << 20));     // 2 MB
  ushort* cpt3   = (ushort*)(w + (15ull << 20));     // 1 MB
  ushort* pdb    = (ushort*)(w + (16ull << 20));     // 0.5 MB
  float*  pdpart = (float*) (w + (17ull << 20));     // 2 MB
  ushort* bufA   = (ushort*)(w + (20ull << 20));     // 64 MB (S in first 32 MB)
  ushort* bufB   = (ushort*)(w + (84ull << 20));     // 64 MB (also L as f32)
  ushort* gbb0   = qb;                                // alias: dead after scores
  ushort* gbb1   = kb;                                // alias: dead after scores
  ushort* gbb2   = cpte0;                             // alias: dead after gemm1/pd
  ushort* S      = bufA;
  float*  L      = (float*)bufB;
  float*  outp   = (float*)d_out;

  hipMemsetAsync(stats, 0, 3 * NB * 2 * sizeof(float), stream);

  proj_kernel<<<dim3(2, 256, 8), 256, 0, stream>>>(x, Wq, Wk, Wv, qb, kb, vp);
  prep_kernel<<<13312, 256, 0, stream>>>(m1w0, m2w0, m1w1, m2w1,
                                         cpte0, cpto0, cpt1, cpt2, cpt3, pdb);
  scores_kernel<<<dim3(8, 64), 256, 0, stream>>>(qb, kb, S);
  // pd_part[t][o] = sum_s pdb[t,s] * cpto0[o,s]   (batch-independent)
  gemm256_kernel<512, true><<<dim3(2, 4, 1), 512, 0, stream>>>(
      pdb, 0, cpto0, 0, pdpart, 1024, nullptr, nullptr);
  // Y1 = S @ cpte0^T + pd_part
  gemm256_kernel<512, false><<<dim3(2, 4, 64), 512, 0, stream>>>(
      S, 512L * 512, cpte0, 0, bufB, 1024, stats, pdpart);
  // pack LN params (qb/kb/cpte0/cpto0 are dead now)
  prep2_kernel<<<3072, 256, 0, stream>>>(ln1g0, ln1b0, ln2g0, ln2b0, ln1g1, ln1b1,
                                         gbb0, gbb1, gbb2);
  apply_kernel<<<dim3(16, 8, 64), 256, 0, stream>>>(bufB, stats, gbb0, bufA);
  gemm256_kernel<1024, false><<<dim3(2, 4, 64), 512, 0, stream>>>(
      bufA, 512L * 1024, cpt1, 0, bufB, 1024, stats + 128, nullptr);
  apply_kernel<<<dim3(16, 8, 64), 256, 0, stream>>>(bufB, stats + 128, gbb1, bufA);
  gemm256_kernel<1024, false><<<dim3(2, 4, 64), 512, 0, stream>>>(
      bufA, 512L * 1024, cpt2, 0, bufB, 1024, stats + 256, nullptr);
  apply_kernel<<<dim3(16, 8, 64), 256, 0, stream>>>(bufB, stats + 256, gbb2, bufA);
  // L[b, a, t] = sum_k cpt3[a,k] * P3'[t,k]   (softmax-ready layout)
  gemm256_kernel<1024, true><<<dim3(2, 2, 64), 512, 0, stream>>>(
      cpt3, 0, bufA, 512L * 1024, L, 512, nullptr, nullptr);
  smax_av_kernel<<<dim3(64, 16), 256, 0, stream>>>(L, vp, outp);
}